// Round 2
// baseline (702.552 us; speedup 1.0000x reference)
//
#include <hip/hip_runtime.h>
#include <hip/hip_bf16.h>

#define N_NODES 100000
#define N_EDGES 1600000
#define N_GRAPHS 512
#define SCAN_CHUNK 1024
#define NCHUNK 98   // ceil(100000/1024)

typedef __attribute__((ext_vector_type(8))) short short8;
typedef __attribute__((ext_vector_type(4))) float f32x4;

// ---- bf16 helpers (raw ushort representation) ----
__device__ __forceinline__ float b2f(ushort u) {
    union { unsigned int i; float f; } c; c.i = ((unsigned int)u) << 16; return c.f;
}
__device__ __forceinline__ float blo(unsigned int u) {
    union { unsigned int i; float f; } c; c.i = u << 16; return c.f;
}
__device__ __forceinline__ float bhi(unsigned int u) {
    union { unsigned int i; float f; } c; c.i = u & 0xffff0000u; return c.f;
}
__device__ __forceinline__ ushort f2b(float f) {  // round-to-nearest-even
    union { float f; unsigned int i; } c; c.f = f;
    unsigned int r = (c.i + 0x7fffu + ((c.i >> 16) & 1u)) >> 16;
    return (ushort)r;
}

// read integer element i from an array that is either int32 (i64flag=0) or int64 (i64flag=1)
__device__ __forceinline__ int idx_at(const void* p, long i, int i64flag) {
    return i64flag ? (int)((const long long*)p)[i] : ((const int*)p)[i];
}

// ---- 0. dtype detection (deterministic, data-driven, graph-safe) ----
// flags[0]: 1 = floats are bf16, 0 = floats are fp32
// flags[1]: 1 = edge_index is int64, 0 = int32
// flags[2]: 1 = batch is int64, 0 = int32
__global__ __launch_bounds__(256) void k_detect(const unsigned int* __restrict__ xw,
                                                const unsigned int* __restrict__ ew,
                                                const int* __restrict__ bw,
                                                int* __restrict__ flags) {
    __shared__ int cf, ce, cb;
    int t = threadIdx.x;
    if (t == 0) { cf = 0; ce = 0; cb = 0; }
    __syncthreads();
    // float test: low-half exponent field of first 256 words of x
    unsigned int w = xw[t];
    unsigned int e = (w >> 7) & 0xffu;
    if (e >= 110u && e <= 130u) atomicAdd(&cf, 1);
    if (t < 128) {
        if (ew[2 * t + 1] != 0u) atomicAdd(&ce, 1);      // odd words of edge_index
        if (bw[99001 + 2 * t] != 0) atomicAdd(&cb, 1);   // odd words (if i64) deep in sorted batch
    }
    __syncthreads();
    if (t == 0) {
        flags[0] = (cf >= 128) ? 1 : 0;
        flags[1] = (ce == 0) ? 1 : 0;
        flags[2] = (cb == 0) ? 1 : 0;
    }
}

// ---- 1. histogram of dst ----
__global__ __launch_bounds__(256) void k_hist(const void* __restrict__ ei,
                                              int* __restrict__ cnt,
                                              const int* __restrict__ flags) {
    int e = blockIdx.x * 256 + threadIdx.x;
    int f = flags[1];
    if (e < N_EDGES) {
        int d = idx_at(ei, (long)N_EDGES + e, f);
        atomicAdd(&cnt[d], 1);
    }
}

// ---- 2a. per-chunk reduce ----
__global__ __launch_bounds__(256) void k_chunk_reduce(const int* __restrict__ cnt,
                                                      int* __restrict__ bsum) {
    int b = blockIdx.x, t = threadIdx.x;
    int base = b * SCAN_CHUNK + t * 4;
    int s = 0;
#pragma unroll
    for (int i = 0; i < 4; ++i) { int idx = base + i; if (idx < N_NODES) s += cnt[idx]; }
    __shared__ int red[256];
    red[t] = s; __syncthreads();
    for (int off = 128; off > 0; off >>= 1) {
        if (t < off) red[t] += red[t + off];
        __syncthreads();
    }
    if (t == 0) bsum[b] = red[0];
}

// ---- 2b. scan of chunk sums (single block) ----
__global__ __launch_bounds__(128) void k_chunk_scan(int* __restrict__ bsum,
                                                    int* __restrict__ rowptr) {
    __shared__ int s[128];
    int t = threadIdx.x;
    int v = (t < NCHUNK) ? bsum[t] : 0;
    s[t] = v; __syncthreads();
    for (int off = 1; off < 128; off <<= 1) {
        int a = (t >= off) ? s[t - off] : 0;
        __syncthreads();
        s[t] += a;
        __syncthreads();
    }
    if (t < NCHUNK) bsum[t] = s[t] - v;        // exclusive chunk offsets
    if (t == 127) rowptr[N_NODES] = s[127];    // total == N_EDGES
}

// ---- 2c. per-chunk scatter: exclusive scan in place + cursor copy ----
__global__ __launch_bounds__(256) void k_chunk_scatter(int* __restrict__ cnt,
                                                       const int* __restrict__ bsum,
                                                       int* __restrict__ cur) {
    int b = blockIdx.x, t = threadIdx.x;
    int base = b * SCAN_CHUNK + t * 4;
    int v[4]; int s = 0;
#pragma unroll
    for (int i = 0; i < 4; ++i) { int idx = base + i; v[i] = (idx < N_NODES) ? cnt[idx] : 0; s += v[i]; }
    __shared__ int sh[256];
    sh[t] = s; __syncthreads();
    int tot = s;
    for (int off = 1; off < 256; off <<= 1) {
        int a = (t >= off) ? sh[t - off] : 0;
        __syncthreads();
        sh[t] += a;
        __syncthreads();
    }
    int pre = sh[t] - tot + bsum[b];
#pragma unroll
    for (int i = 0; i < 4; ++i) {
        int idx = base + i;
        if (idx < N_NODES) { cnt[idx] = pre; cur[idx] = pre; pre += v[i]; }
    }
}

// ---- 3. CSR bucket fill ----
__global__ __launch_bounds__(256) void k_fill(const void* __restrict__ ei,
                                              int* __restrict__ cur,
                                              int* __restrict__ csr,
                                              const int* __restrict__ flags) {
    int e = blockIdx.x * 256 + threadIdx.x;
    int f = flags[1];
    if (e < N_EDGES) {
        int s = idx_at(ei, e, f);
        int d = idx_at(ei, (long)N_EDGES + e, f);
        int pos = atomicAdd(&cur[d], 1);
        csr[pos] = s;
    }
}

// ---- 4. mean aggregation: one wave per node ----
// xin dtype: layer1 follows flags[0] (fp32 or bf16); layer2 always bf16.
__global__ __launch_bounds__(256) void k_agg(const void* __restrict__ xin,
                                             const int* __restrict__ rowptr,
                                             const int* __restrict__ csr,
                                             ushort* __restrict__ mout,
                                             const int* __restrict__ flags,
                                             int may_be_f32) {
    int wid = blockIdx.x * 4 + (threadIdx.x >> 6);
    int lane = threadIdx.x & 63;
    if (wid >= N_NODES) return;
    bool f32 = may_be_f32 && (flags[0] == 0);
    int beg = rowptr[wid], end = rowptr[wid + 1];
    float a0 = 0.f, a1 = 0.f;
    if (f32) {
        const float2* xr = (const float2*)xin;
        int j = beg;
        for (; j + 1 < end; j += 2) {
            int s0 = csr[j], s1 = csr[j + 1];
            float2 p0 = xr[s0 * 64 + lane];
            float2 p1 = xr[s1 * 64 + lane];
            a0 += p0.x + p1.x; a1 += p0.y + p1.y;
        }
        if (j < end) {
            float2 p0 = xr[csr[j] * 64 + lane];
            a0 += p0.x; a1 += p0.y;
        }
    } else {
        const unsigned int* xr = (const unsigned int*)xin;
        int j = beg;
        for (; j + 1 < end; j += 2) {
            int s0 = csr[j], s1 = csr[j + 1];
            unsigned int p0 = xr[s0 * 64 + lane];
            unsigned int p1 = xr[s1 * 64 + lane];
            a0 += blo(p0) + blo(p1); a1 += bhi(p0) + bhi(p1);
        }
        if (j < end) {
            unsigned int p0 = xr[csr[j] * 64 + lane];
            a0 += blo(p0); a1 += bhi(p0);
        }
    }
    int deg = end - beg;
    float sc = (deg > 0) ? 1.f / (float)deg : 0.f;
    unsigned int packed = ((unsigned int)f2b(a1 * sc) << 16) | (unsigned int)f2b(a0 * sc);
    ((unsigned int*)mout)[wid * 64 + lane] = packed;
}

// ---- 5. fused SAGE linear: out = relu([A0|A1] @ [Wl;Wr]^T + bias) ----
// A0 = mean (always bf16). A1 dtype: follows flags[0] if a1_follows_flag, else bf16.
// Weights/bias dtype per flags[0]. K=256, Dout=128, MFMA 16x16x32 bf16.
__global__ __launch_bounds__(256) void k_gemm(const ushort* __restrict__ A0,
                                              const void* __restrict__ A1,
                                              const void* __restrict__ Wl,
                                              const void* __restrict__ Wr,
                                              const void* __restrict__ bias,
                                              ushort* __restrict__ out,
                                              const int* __restrict__ flags,
                                              int a1_follows_flag) {
    __shared__ short Ws[4096 * 8];  // 64 KiB, fragment-interleaved weights
    int t = threadIdx.x;
    bool wf32 = (flags[0] == 0);
    bool a1f32 = a1_follows_flag && wf32;

    if (wf32) {
#pragma unroll
        for (int i = 0; i < 16; ++i) {
            int f = i * 256 + t;
            int lane = f & 63, kk = (f >> 6) & 7, tile = f >> 9;
            int o = tile * 16 + (lane & 15);
            int k0 = kk * 32 + ((lane >> 4) * 8);
            const float* wsrc = (k0 < 128) ? ((const float*)Wl + o * 128 + k0)
                                           : ((const float*)Wr + o * 128 + (k0 - 128));
            short8 s;
#pragma unroll
            for (int j = 0; j < 8; ++j) s[j] = (short)f2b(wsrc[j]);
            *(short8*)&Ws[f * 8] = s;
        }
    } else {
#pragma unroll
        for (int i = 0; i < 16; ++i) {
            int f = i * 256 + t;
            int lane = f & 63, kk = (f >> 6) & 7, tile = f >> 9;
            int o = tile * 16 + (lane & 15);
            int k0 = kk * 32 + ((lane >> 4) * 8);
            const ushort* wsrc = (k0 < 128) ? ((const ushort*)Wl + o * 128 + k0)
                                            : ((const ushort*)Wr + o * 128 + (k0 - 128));
            *(short8*)&Ws[f * 8] = *(const short8*)wsrc;
        }
    }
    __syncthreads();

    int wid = t >> 6, lane = t & 63;
    long nbase = (long)blockIdx.x * 64 + (long)wid * 16;
    int arow = (int)nbase + (lane & 15);
    if (arow >= N_NODES) arow = N_NODES - 1;   // clamp (stores are guarded)
    int kq = (lane >> 4) * 8;

    short8 afrag[8];
#pragma unroll
    for (int kk = 0; kk < 8; ++kk) {
        int k0 = kk * 32 + kq;
        if (k0 < 128) {
            afrag[kk] = *(const short8*)(A0 + (long)arow * 128 + k0);
        } else {
            int k1 = k0 - 128;
            if (a1f32) {
                const float* ap = (const float*)A1 + (long)arow * 128 + k1;
                short8 s;
#pragma unroll
                for (int j = 0; j < 8; ++j) s[j] = (short)f2b(ap[j]);
                afrag[kk] = s;
            } else {
                afrag[kk] = *(const short8*)((const ushort*)A1 + (long)arow * 128 + k1);
            }
        }
    }

#pragma unroll
    for (int tile = 0; tile < 8; ++tile) {
        f32x4 acc = {0.f, 0.f, 0.f, 0.f};
#pragma unroll
        for (int kk = 0; kk < 8; ++kk) {
            short8 bfrag = *(short8*)&Ws[((tile * 8 + kk) * 64 + lane) * 8];
            acc = __builtin_amdgcn_mfma_f32_16x16x32_bf16(afrag[kk], bfrag, acc, 0, 0, 0);
        }
        int o = tile * 16 + (lane & 15);
        float bo = wf32 ? ((const float*)bias)[o] : b2f(((const ushort*)bias)[o]);
#pragma unroll
        for (int r = 0; r < 4; ++r) {
            long node = nbase + (lane >> 4) * 4 + r;
            if (node < N_NODES) {
                float v = acc[r] + bo;
                v = v > 0.f ? v : 0.f;
                out[node * 128 + o] = f2b(v);
            }
        }
    }
}

// ---- 6. fused global mean pool + classifier + log_softmax ----
__global__ __launch_bounds__(128) void k_pool_cls(const ushort* __restrict__ h2,
                                                  const void* __restrict__ batch,
                                                  const void* __restrict__ Wf,
                                                  const void* __restrict__ bfv,
                                                  void* __restrict__ outp,
                                                  const int* __restrict__ flags) {
    int g = blockIdx.x, t = threadIdx.x;  // 128 threads
    bool f32 = (flags[0] == 0);
    int b64 = flags[2];
    __shared__ int rng[2];
    __shared__ float gv[128];
    __shared__ float lg[10];
    if (t < 2) {
        int v = g + t, lo = 0, hi = N_NODES;
        while (lo < hi) {
            int mid = (lo + hi) >> 1;
            if (idx_at(batch, mid, b64) < v) lo = mid + 1; else hi = mid;
        }
        rng[t] = lo;
    }
    __syncthreads();
    int lo = rng[0], hi = rng[1];
    float acc = 0.f;
    for (int n = lo; n < hi; ++n) acc += b2f(h2[(long)n * 128 + t]);
    float c = (hi > lo) ? (float)(hi - lo) : 1.f;
    gv[t] = acc / c;
    __syncthreads();
    if (t < 10) {
        float s = f32 ? ((const float*)bfv)[t] : b2f(((const ushort*)bfv)[t]);
        for (int k = 0; k < 128; ++k) {
            float wv = f32 ? ((const float*)Wf)[t * 128 + k] : b2f(((const ushort*)Wf)[t * 128 + k]);
            s += gv[k] * wv;
        }
        lg[t] = s;
    }
    __syncthreads();
    if (t == 0) {
        float mx = lg[0];
        for (int i = 1; i < 10; ++i) mx = fmaxf(mx, lg[i]);
        float se = 0.f;
        for (int i = 0; i < 10; ++i) se += expf(lg[i] - mx);
        float lse = mx + logf(se);
        for (int i = 0; i < 10; ++i) {
            float v = lg[i] - lse;
            if (f32) ((float*)outp)[g * 10 + i] = v;
            else     ((ushort*)outp)[g * 10 + i] = f2b(v);
        }
    }
}

extern "C" void kernel_launch(void* const* d_in, const int* in_sizes, int n_in,
                              void* d_out, int out_size, void* d_ws, size_t ws_size,
                              hipStream_t stream) {
    const void* x     = d_in[0];
    const void* ei    = d_in[1];
    const void* batch = d_in[2];
    const void* W1l = d_in[3];
    const void* b1  = d_in[4];
    const void* W1r = d_in[5];
    const void* W2l = d_in[6];
    const void* b2  = d_in[7];
    const void* W2r = d_in[8];
    const void* Wf  = d_in[9];
    const void* bf_ = d_in[10];

    // workspace layout
    char* w = (char*)d_ws;
    int* rowptr  = (int*)(w);                    // (N+1) ints            [0, 400128)
    int* cur     = (int*)(w + 400128);           // N ints                [400128, 800128)
    int* bsum    = (int*)(w + 800128);           // 128 ints              [800128, 800640)
    int* flags   = (int*)(w + 800640);           // 3 ints                [800640, 800768)
    int* csr     = (int*)(w + 800768);           // E ints                [800768, 7200768)
    ushort* mbuf = (ushort*)(w + 7200768);       // N*128 bf16            [7200768, 32800768)
    ushort* h1   = (ushort*)(w + 32800768);      // N*128 bf16            [32800768, 58400768)
    ushort* h2   = mbuf;  // alias: k_gemm layer2 reads its own A0 rows before storing them
    // total: 58,400,768 bytes

    hipMemsetAsync(rowptr, 0, (N_NODES + 1) * sizeof(int), stream);

    dim3 blk256(256), blk128(128);
    int egrid = (N_EDGES + 255) / 256;           // 6250

    k_detect<<<1, blk256, 0, stream>>>((const unsigned int*)x, (const unsigned int*)ei,
                                       (const int*)batch, flags);
    k_hist<<<egrid, blk256, 0, stream>>>(ei, rowptr, flags);
    k_chunk_reduce<<<NCHUNK, blk256, 0, stream>>>(rowptr, bsum);
    k_chunk_scan<<<1, blk128, 0, stream>>>(bsum, rowptr);
    k_chunk_scatter<<<NCHUNK, blk256, 0, stream>>>(rowptr, bsum, cur);
    k_fill<<<egrid, blk256, 0, stream>>>(ei, cur, csr, flags);

    int agrid = (N_NODES + 3) / 4;               // 25000 (wave per node)
    int ggrid = (N_NODES + 63) / 64;             // 1563

    // layer 1
    k_agg<<<agrid, blk256, 0, stream>>>(x, rowptr, csr, mbuf, flags, 1);
    k_gemm<<<ggrid, blk256, 0, stream>>>(mbuf, x, W1l, W1r, b1, h1, flags, 1);
    // layer 2
    k_agg<<<agrid, blk256, 0, stream>>>(h1, rowptr, csr, mbuf, flags, 0);
    k_gemm<<<ggrid, blk256, 0, stream>>>(mbuf, h1, W2l, W2r, b2, h2, flags, 0);
    // pool + classify
    k_pool_cls<<<N_GRAPHS, blk128, 0, stream>>>(h2, batch, Wf, bf_, d_out, flags);
}

// Round 3
// 536.089 us; speedup vs baseline: 1.3105x; 1.3105x over previous
//
#include <hip/hip_runtime.h>
#include <hip/hip_bf16.h>

#define N_NODES 100000
#define N_EDGES 1600000
#define N_GRAPHS 512
#define NB 128                 // coarse dst-buckets
#define NPB 782                // nodes per bucket (128*782 = 100096 >= 100000)
#define CHUNK 12500            // edges per binning block (128*12500 = 1.6M exact)
#define STAGE 14336            // LDS csr staging entries per bucket (mean 12500, sd ~112)

typedef __attribute__((ext_vector_type(8))) short short8;
typedef __attribute__((ext_vector_type(4))) float f32x4;

// ---- bf16 helpers (raw ushort representation) ----
__device__ __forceinline__ float b2f(ushort u) {
    union { unsigned int i; float f; } c; c.i = ((unsigned int)u) << 16; return c.f;
}
__device__ __forceinline__ float blo(unsigned int u) {
    union { unsigned int i; float f; } c; c.i = u << 16; return c.f;
}
__device__ __forceinline__ float bhi(unsigned int u) {
    union { unsigned int i; float f; } c; c.i = u & 0xffff0000u; return c.f;
}
__device__ __forceinline__ ushort f2b(float f) {  // round-to-nearest-even
    union { float f; unsigned int i; } c; c.f = f;
    unsigned int r = (c.i + 0x7fffu + ((c.i >> 16) & 1u)) >> 16;
    return (ushort)r;
}

// integer element i from array that is int32 (f=0) or int64 (f=1)
__device__ __forceinline__ int idx_at(const void* p, long i, int f) {
    return f ? (int)((const long long*)p)[i] : ((const int*)p)[i];
}

// ---- 0. dtype detection (unchanged from passing round) ----
// flags[0]: 1 = floats bf16, 0 = fp32 ; flags[1]: edge int64? ; flags[2]: batch int64?
__global__ __launch_bounds__(256) void k_detect(const unsigned int* __restrict__ xw,
                                                const unsigned int* __restrict__ ew,
                                                const int* __restrict__ bw,
                                                int* __restrict__ flags) {
    __shared__ int cf, ce, cb;
    int t = threadIdx.x;
    if (t == 0) { cf = 0; ce = 0; cb = 0; }
    __syncthreads();
    unsigned int w = xw[t];
    unsigned int e = (w >> 7) & 0xffu;
    if (e >= 110u && e <= 130u) atomicAdd(&cf, 1);
    if (t < 128) {
        if (ew[2 * t + 1] != 0u) atomicAdd(&ce, 1);
        if (bw[99001 + 2 * t] != 0) atomicAdd(&cb, 1);
    }
    __syncthreads();
    if (t == 0) {
        flags[0] = (cf >= 128) ? 1 : 0;
        flags[1] = (ce == 0) ? 1 : 0;
        flags[2] = (cb == 0) ? 1 : 0;
    }
}

// ---- 0b. convert x to bf16 if fp32 (else no-op; consumers use original) ----
__global__ __launch_bounds__(256) void k_cvt_x(const float4* __restrict__ xf,
                                               ushort* __restrict__ xbf,
                                               const int* __restrict__ flags) {
    if (flags[0] != 0) return;   // already bf16
    long n4 = (long)N_NODES * 128 / 4;  // 3.2M float4
    for (long i = blockIdx.x * 256 + threadIdx.x; i < n4; i += (long)gridDim.x * 256) {
        float4 v = xf[i];
        ushort* o = xbf + i * 4;
        o[0] = f2b(v.x); o[1] = f2b(v.y); o[2] = f2b(v.z); o[3] = f2b(v.w);
    }
}

// ---- 0c. convert/copy GEMM weights+biases to bf16 (wbf layout in shorts):
// W1l@0  W1r@16384  W2l@32768  W2r@49152  b1@65536  b2@65664   (total 65792)
__global__ __launch_bounds__(256) void k_cvt_w(const void* W1l, const void* W1r,
                                               const void* W2l, const void* W2r,
                                               const void* b1,  const void* b2,
                                               ushort* __restrict__ wbf,
                                               const int* __restrict__ flags) {
    int idx = blockIdx.x * 256 + threadIdx.x;
    if (idx >= 65792) return;
    const void* src; int off;
    if      (idx < 16384) { src = W1l; off = idx; }
    else if (idx < 32768) { src = W1r; off = idx - 16384; }
    else if (idx < 49152) { src = W2l; off = idx - 32768; }
    else if (idx < 65536) { src = W2r; off = idx - 49152; }
    else if (idx < 65664) { src = b1;  off = idx - 65536; }
    else                  { src = b2;  off = idx - 65664; }
    wbf[idx] = (flags[0] != 0) ? ((const ushort*)src)[off]
                               : f2b(((const float*)src)[off]);
}

// ---- 1. per-block bucket histogram: blkcnt[blk][bkt] ----
__global__ __launch_bounds__(256) void k_bhist(const void* __restrict__ ei,
                                               int* __restrict__ blkcnt,
                                               const int* __restrict__ flags) {
    __shared__ int h[NB];
    int t = threadIdx.x, blk = blockIdx.x;
    int f = flags[1];
    for (int j = t; j < NB; j += 256) h[j] = 0;
    __syncthreads();
    int lo = blk * CHUNK, hi = lo + CHUNK;
    for (int e = lo + t; e < hi; e += 256) {
        int d = idx_at(ei, (long)N_EDGES + e, f);
        atomicAdd(&h[d / NPB], 1);
    }
    __syncthreads();
    if (t < NB) blkcnt[blk * NB + t] = h[t];
}

// ---- 2. scan: bucketBase + per-(block,bucket) bases (1 block, 128 threads) ----
__global__ __launch_bounds__(128) void k_bscan(const int* __restrict__ blkcnt,
                                               int* __restrict__ bucketBase,
                                               int* __restrict__ blkbase) {
    __shared__ int s[NB];
    int t = threadIdx.x;
    int tot = 0;
    for (int blk = 0; blk < NB; ++blk) tot += blkcnt[blk * NB + t];
    s[t] = tot; __syncthreads();
    for (int off = 1; off < NB; off <<= 1) {
        int a = (t >= off) ? s[t - off] : 0;
        __syncthreads();
        s[t] += a;
        __syncthreads();
    }
    int excl = s[t] - tot;
    bucketBase[t] = excl;
    if (t == NB - 1) bucketBase[NB] = s[NB - 1];
    int run = excl;
    for (int blk = 0; blk < NB; ++blk) {
        blkbase[blk * NB + t] = run;
        run += blkcnt[blk * NB + t];
    }
}

// ---- 3. bin edges into buckets (private contiguous runs, no global atomics) ----
__global__ __launch_bounds__(256) void k_bin(const void* __restrict__ ei,
                                             const int* __restrict__ blkbase,
                                             int2* __restrict__ binned,
                                             const int* __restrict__ flags) {
    __shared__ int bb[NB];
    __shared__ int rank[NB];
    int t = threadIdx.x, blk = blockIdx.x;
    int f = flags[1];
    for (int j = t; j < NB; j += 256) { bb[j] = blkbase[blk * NB + j]; rank[j] = 0; }
    __syncthreads();
    int lo = blk * CHUNK, hi = lo + CHUNK;
    for (int e = lo + t; e < hi; e += 256) {
        int s = idx_at(ei, e, f);
        int d = idx_at(ei, (long)N_EDGES + e, f);
        int b = d / NPB;
        int r = atomicAdd(&rank[b], 1);
        binned[bb[b] + r] = make_int2(s, d);
    }
}

// ---- 4. per-bucket CSR: LDS count+scan+scatter, coalesced flush ----
__global__ __launch_bounds__(256) void k_csr(const int2* __restrict__ binned,
                                             const int* __restrict__ bucketBase,
                                             int* __restrict__ rowptr,
                                             int* __restrict__ csr) {
    __shared__ int cnt[784];      // per-node counts, then reused as rank
    __shared__ int sc[784];       // exclusive scan
    __shared__ int sh[256];
    __shared__ int stage[STAGE];  // 56 KB csr staging
    int t = threadIdx.x, b = blockIdx.x;
    int nodeLo = b * NPB;
    int nC = N_NODES - nodeLo; if (nC > NPB) nC = NPB;
    int eBase = bucketBase[b], eEnd = bucketBase[b + 1];

    for (int j = t; j < 784; j += 256) cnt[j] = 0;
    __syncthreads();
    for (int i = eBase + t; i < eEnd; i += 256)
        atomicAdd(&cnt[binned[i].y - nodeLo], 1);
    __syncthreads();
    // exclusive scan of cnt[0..784) -> sc (4 per thread + block scan)
    int base = t * 4, v[4], ssum = 0;
#pragma unroll
    for (int j = 0; j < 4; ++j) { v[j] = (base + j < 784) ? cnt[base + j] : 0; ssum += v[j]; }
    sh[t] = ssum; __syncthreads();
    int tot = ssum;
    for (int off = 1; off < 256; off <<= 1) {
        int a = (t >= off) ? sh[t - off] : 0;
        __syncthreads();
        sh[t] += a;
        __syncthreads();
    }
    int pre = sh[t] - tot;
#pragma unroll
    for (int j = 0; j < 4; ++j) {
        if (base + j < 784) sc[base + j] = pre;
        pre += v[j];
    }
    __syncthreads();
    // rowptr for this node range (+ final sentinel)
    for (int j = t; j < nC; j += 256) rowptr[nodeLo + j] = eBase + sc[j];
    if (b == NB - 1 && t == 0) rowptr[N_NODES] = eEnd;
    // reuse cnt as rank
    for (int j = t; j < 784; j += 256) cnt[j] = 0;
    __syncthreads();
    for (int i = eBase + t; i < eEnd; i += 256) {
        int2 p = binned[i];
        int loc = p.y - nodeLo;
        int pos = sc[loc] + atomicAdd(&cnt[loc], 1);
        if (pos < STAGE) stage[pos] = p.x;
        else csr[eBase + pos] = p.x;   // overflow fallback (statistically never)
    }
    __syncthreads();
    int eCnt = eEnd - eBase; if (eCnt > STAGE) eCnt = STAGE;
    for (int j = t; j < eCnt; j += 256) csr[eBase + j] = stage[j];
}

// ---- 5. mean aggregation: one wave per node, bf16 input always ----
__global__ __launch_bounds__(256) void k_agg(const ushort* __restrict__ xa,
                                             const ushort* __restrict__ xb,
                                             const int* __restrict__ rowptr,
                                             const int* __restrict__ csr,
                                             ushort* __restrict__ mout,
                                             const int* __restrict__ flags,
                                             int use_sel) {
    int wid = blockIdx.x * 4 + (threadIdx.x >> 6);
    int lane = threadIdx.x & 63;
    if (wid >= N_NODES) return;
    const ushort* xin = use_sel ? (flags[0] ? xa : xb) : xa;
    int beg = rowptr[wid], end = rowptr[wid + 1];
    const unsigned int* xr = (const unsigned int*)xin;
    float a0 = 0.f, a1 = 0.f;
    int j = beg;
    for (; j + 1 < end; j += 2) {
        int s0 = csr[j], s1 = csr[j + 1];
        unsigned int p0 = xr[s0 * 64 + lane];
        unsigned int p1 = xr[s1 * 64 + lane];
        a0 += blo(p0) + blo(p1); a1 += bhi(p0) + bhi(p1);
    }
    if (j < end) {
        unsigned int p0 = xr[csr[j] * 64 + lane];
        a0 += blo(p0); a1 += bhi(p0);
    }
    int deg = end - beg;
    float scale = (deg > 0) ? 1.f / (float)deg : 0.f;
    unsigned int packed = ((unsigned int)f2b(a1 * scale) << 16) | (unsigned int)f2b(a0 * scale);
    ((unsigned int*)mout)[wid * 64 + lane] = packed;
}

// ---- 6. fused SAGE linear: out = relu([A0|A1] @ [Wl;Wr]^T + b), all bf16 ----
__global__ __launch_bounds__(256) void k_gemm(const ushort* __restrict__ A0,
                                              const ushort* __restrict__ A1a,
                                              const ushort* __restrict__ A1b,
                                              const ushort* __restrict__ Wl,
                                              const ushort* __restrict__ Wr,
                                              const ushort* __restrict__ bias,
                                              ushort* __restrict__ out,
                                              const int* __restrict__ flags,
                                              int use_sel) {
    __shared__ short Ws[4096 * 8];  // 64 KiB fragment-interleaved weights
    int t = threadIdx.x;
    const ushort* A1 = use_sel ? (flags[0] ? A1a : A1b) : A1a;
#pragma unroll
    for (int i = 0; i < 16; ++i) {
        int f = i * 256 + t;
        int lane = f & 63, kk = (f >> 6) & 7, tile = f >> 9;
        int o = tile * 16 + (lane & 15);
        int k0 = kk * 32 + ((lane >> 4) * 8);
        const ushort* wsrc = (k0 < 128) ? (Wl + o * 128 + k0)
                                        : (Wr + o * 128 + (k0 - 128));
        *(short8*)&Ws[f * 8] = *(const short8*)wsrc;
    }
    __syncthreads();

    int wid = t >> 6, lane = t & 63;
    long nbase = (long)blockIdx.x * 64 + (long)wid * 16;
    int arow = (int)nbase + (lane & 15);
    if (arow >= N_NODES) arow = N_NODES - 1;   // clamp (stores guarded)
    int kq = (lane >> 4) * 8;

    short8 afrag[8];
#pragma unroll
    for (int kk = 0; kk < 8; ++kk) {
        int k0 = kk * 32 + kq;
        afrag[kk] = (k0 < 128)
            ? *(const short8*)(A0 + (long)arow * 128 + k0)
            : *(const short8*)(A1 + (long)arow * 128 + (k0 - 128));
    }

#pragma unroll
    for (int tile = 0; tile < 8; ++tile) {
        f32x4 acc = {0.f, 0.f, 0.f, 0.f};
#pragma unroll
        for (int kk = 0; kk < 8; ++kk) {
            short8 bfrag = *(short8*)&Ws[((tile * 8 + kk) * 64 + lane) * 8];
            acc = __builtin_amdgcn_mfma_f32_16x16x32_bf16(afrag[kk], bfrag, acc, 0, 0, 0);
        }
        int o = tile * 16 + (lane & 15);
        float bo = b2f(bias[o]);
#pragma unroll
        for (int r = 0; r < 4; ++r) {
            long node = nbase + (lane >> 4) * 4 + r;
            if (node < N_NODES) {
                float v = acc[r] + bo;
                v = v > 0.f ? v : 0.f;
                out[node * 128 + o] = f2b(v);
            }
        }
    }
}

// ---- 7. fused global mean pool + classifier + log_softmax ----
__global__ __launch_bounds__(128) void k_pool_cls(const ushort* __restrict__ h2,
                                                  const void* __restrict__ batch,
                                                  const void* __restrict__ Wf,
                                                  const void* __restrict__ bfv,
                                                  void* __restrict__ outp,
                                                  const int* __restrict__ flags) {
    int g = blockIdx.x, t = threadIdx.x;  // 128 threads
    bool f32 = (flags[0] == 0);
    int b64 = flags[2];
    __shared__ int rng[2];
    __shared__ float gv[128];
    __shared__ float lg[10];
    if (t < 2) {
        int v = g + t, lo = 0, hi = N_NODES;
        while (lo < hi) {
            int mid = (lo + hi) >> 1;
            if (idx_at(batch, mid, b64) < v) lo = mid + 1; else hi = mid;
        }
        rng[t] = lo;
    }
    __syncthreads();
    int lo = rng[0], hi = rng[1];
    float acc = 0.f;
    for (int n = lo; n < hi; ++n) acc += b2f(h2[(long)n * 128 + t]);
    float c = (hi > lo) ? (float)(hi - lo) : 1.f;
    gv[t] = acc / c;
    __syncthreads();
    if (t < 10) {
        float s = f32 ? ((const float*)bfv)[t] : b2f(((const ushort*)bfv)[t]);
        for (int k = 0; k < 128; ++k) {
            float wv = f32 ? ((const float*)Wf)[t * 128 + k] : b2f(((const ushort*)Wf)[t * 128 + k]);
            s += gv[k] * wv;
        }
        lg[t] = s;
    }
    __syncthreads();
    if (t == 0) {
        float mx = lg[0];
        for (int i = 1; i < 10; ++i) mx = fmaxf(mx, lg[i]);
        float se = 0.f;
        for (int i = 0; i < 10; ++i) se += expf(lg[i] - mx);
        float lse = mx + logf(se);
        for (int i = 0; i < 10; ++i) {
            float v = lg[i] - lse;
            if (f32) ((float*)outp)[g * 10 + i] = v;
            else     ((ushort*)outp)[g * 10 + i] = f2b(v);
        }
    }
}

extern "C" void kernel_launch(void* const* d_in, const int* in_sizes, int n_in,
                              void* d_out, int out_size, void* d_ws, size_t ws_size,
                              hipStream_t stream) {
    const void* x     = d_in[0];
    const void* ei    = d_in[1];
    const void* batch = d_in[2];
    const void* W1l = d_in[3];
    const void* b1  = d_in[4];
    const void* W1r = d_in[5];
    const void* W2l = d_in[6];
    const void* b2  = d_in[7];
    const void* W2r = d_in[8];
    const void* Wf  = d_in[9];
    const void* bf_ = d_in[10];

    // workspace layout (256B-aligned)
    char* w = (char*)d_ws;
    int* flags      = (int*)(w + 0);             // 3 ints
    int* bucketBase = (int*)(w + 640);           // 129 ints
    int* blkcnt     = (int*)(w + 1280);          // 128*128 ints
    int* blkbase    = (int*)(w + 66816);         // 128*128 ints
    int* rowptr     = (int*)(w + 132608);        // 100001 ints
    ushort* wbf     = (ushort*)(w + 532736);     // 65792 shorts (bf16 weights)
    int* csr        = (int*)(w + 674304);        // 1.6M ints
    ushort* xbf     = (ushort*)(w + 7074304);    // 12.8M bf16
    ushort* mbuf    = (ushort*)(w + 32674304);   // 12.8M bf16  (also h2)
    ushort* h1      = (ushort*)(w + 58274304);   // 12.8M bf16
    int2* binned    = (int2*)(w + 58274304);     // 1.6M int2 — aliases h1 (dead before h1 written)
    ushort* h2      = mbuf;                      // gemm L2 is row-exclusive per block
    // high-water: 83,874,304 bytes (< 84,000,768 verified available)

    dim3 blk256(256), blk128(128);

    k_detect<<<1, blk256, 0, stream>>>((const unsigned int*)x, (const unsigned int*)ei,
                                       (const int*)batch, flags);
    k_cvt_x<<<2048, blk256, 0, stream>>>((const float4*)x, xbf, flags);
    k_cvt_w<<<257, blk256, 0, stream>>>(W1l, W1r, W2l, W2r, b1, b2, wbf, flags);

    k_bhist<<<NB, blk256, 0, stream>>>(ei, blkcnt, flags);
    k_bscan<<<1, blk128, 0, stream>>>(blkcnt, bucketBase, blkbase);
    k_bin<<<NB, blk256, 0, stream>>>(ei, blkbase, binned, flags);
    k_csr<<<NB, blk256, 0, stream>>>(binned, bucketBase, rowptr, csr);

    int agrid = (N_NODES + 3) / 4;               // 25000 (wave per node)
    int ggrid = (N_NODES + 63) / 64;             // 1563

    // layer 1
    k_agg<<<agrid, blk256, 0, stream>>>((const ushort*)x, xbf, rowptr, csr, mbuf, flags, 1);
    k_gemm<<<ggrid, blk256, 0, stream>>>(mbuf, (const ushort*)x, xbf,
                                         wbf + 0, wbf + 16384, wbf + 65536, h1, flags, 1);
    // layer 2
    k_agg<<<agrid, blk256, 0, stream>>>(h1, h1, rowptr, csr, mbuf, flags, 0);
    k_gemm<<<ggrid, blk256, 0, stream>>>(mbuf, h1, h1,
                                         wbf + 32768, wbf + 49152, wbf + 65664, h2, flags, 0);
    // pool + classify
    k_pool_cls<<<N_GRAPHS, blk128, 0, stream>>>(h2, batch, Wf, bf_, d_out, flags);
}

// Round 4
// 426.109 us; speedup vs baseline: 1.6488x; 1.2581x over previous
//
#include <hip/hip_runtime.h>
#include <hip/hip_bf16.h>

#define N_NODES 100000
#define N_EDGES 1600000
#define N_GRAPHS 512
#define NB 256                 // coarse dst-buckets
#define NPB 391                // nodes per bucket (256*391 = 100096 >= 100000)
#define CHUNK 6250             // edges per binning block (256*6250 = 1.6M exact)
#define STAGE 7680             // LDS csr staging per bucket (mean 6250, sd ~79)

typedef __attribute__((ext_vector_type(8))) short short8;
typedef __attribute__((ext_vector_type(4))) float f32x4;

// ---- bf16 helpers ----
__device__ __forceinline__ float b2f(ushort u) {
    union { unsigned int i; float f; } c; c.i = ((unsigned int)u) << 16; return c.f;
}
__device__ __forceinline__ float blo(unsigned int u) {
    union { unsigned int i; float f; } c; c.i = u << 16; return c.f;
}
__device__ __forceinline__ float bhi(unsigned int u) {
    union { unsigned int i; float f; } c; c.i = u & 0xffff0000u; return c.f;
}
__device__ __forceinline__ ushort f2b(float f) {  // round-to-nearest-even
    union { float f; unsigned int i; } c; c.f = f;
    unsigned int r = (c.i + 0x7fffu + ((c.i >> 16) & 1u)) >> 16;
    return (ushort)r;
}
__device__ __forceinline__ int idx_at(const void* p, long i, int f) {
    return f ? (int)((const long long*)p)[i] : ((const int*)p)[i];
}

// ---- 0. dtype detection ----
// flags[0]: 1 = floats bf16, 0 = fp32 ; flags[1]: edge int64? ; flags[2]: batch int64?
__global__ __launch_bounds__(256) void k_detect(const unsigned int* __restrict__ xw,
                                                const unsigned int* __restrict__ ew,
                                                const int* __restrict__ bw,
                                                int* __restrict__ flags) {
    __shared__ int cf, ce, cb;
    int t = threadIdx.x;
    if (t == 0) { cf = 0; ce = 0; cb = 0; }
    __syncthreads();
    unsigned int w = xw[t];
    unsigned int e = (w >> 7) & 0xffu;
    if (e >= 110u && e <= 130u) atomicAdd(&cf, 1);
    if (t < 128) {
        if (ew[2 * t + 1] != 0u) atomicAdd(&ce, 1);
        if (bw[99001 + 2 * t] != 0) atomicAdd(&cb, 1);
    }
    __syncthreads();
    if (t == 0) {
        flags[0] = (cf >= 128) ? 1 : 0;
        flags[1] = (ce == 0) ? 1 : 0;
        flags[2] = (cb == 0) ? 1 : 0;
    }
}

// ---- 1. fused prep: [0,NB) bucket-hist | [NB,NB+2048) cvt_x | rest cvt_w ----
__global__ __launch_bounds__(256) void k_prep(const void* __restrict__ ei,
                                              const float4* __restrict__ xf,
                                              ushort* __restrict__ xbf,
                                              const void* W1l, const void* W1r,
                                              const void* W2l, const void* W2r,
                                              const void* b1,  const void* b2,
                                              ushort* __restrict__ wbf,
                                              int* __restrict__ blkcnt,
                                              const int* __restrict__ flags) {
    int b = blockIdx.x, t = threadIdx.x;
    if (b < NB) {
        // bucket histogram of this block's edge chunk
        __shared__ int h[NB];
        int f = flags[1];
        for (int j = t; j < NB; j += 256) h[j] = 0;
        __syncthreads();
        int lo = b * CHUNK, hi = lo + CHUNK;
        for (int e = lo + t; e < hi; e += 256) {
            int d = idx_at(ei, (long)N_EDGES + e, f);
            atomicAdd(&h[d / NPB], 1);
        }
        __syncthreads();
        if (t < NB) blkcnt[b * NB + t] = h[t];
    } else if (b < NB + 2048) {
        if (flags[0] != 0) return;   // already bf16
        int vb = b - NB;
        long n4 = (long)N_NODES * 128 / 4;  // 3.2M float4
        for (long i = (long)vb * 256 + t; i < n4; i += 2048L * 256) {
            float4 v = xf[i];
            ushort* o = xbf + i * 4;
            o[0] = f2b(v.x); o[1] = f2b(v.y); o[2] = f2b(v.z); o[3] = f2b(v.w);
        }
    } else {
        // weights+biases -> bf16: W1l@0 W1r@16384 W2l@32768 W2r@49152 b1@65536 b2@65664
        int idx = (b - NB - 2048) * 256 + t;
        if (idx >= 65792) return;
        const void* src; int off;
        if      (idx < 16384) { src = W1l; off = idx; }
        else if (idx < 32768) { src = W1r; off = idx - 16384; }
        else if (idx < 49152) { src = W2l; off = idx - 32768; }
        else if (idx < 65536) { src = W2r; off = idx - 49152; }
        else if (idx < 65664) { src = b1;  off = idx - 65536; }
        else                  { src = b2;  off = idx - 65664; }
        wbf[idx] = (flags[0] != 0) ? ((const ushort*)src)[off]
                                   : f2b(((const float*)src)[off]);
    }
}

// ---- 2. scan: bucketBase + per-(block,bucket) bases (1 block, NB threads) ----
__global__ __launch_bounds__(NB) void k_bscan(const int* __restrict__ blkcnt,
                                              int* __restrict__ bucketBase,
                                              int* __restrict__ blkbase) {
    __shared__ int s[NB];
    int t = threadIdx.x;
    int tot = 0;
    for (int blk = 0; blk < NB; ++blk) tot += blkcnt[blk * NB + t];
    s[t] = tot; __syncthreads();
    for (int off = 1; off < NB; off <<= 1) {
        int a = (t >= off) ? s[t - off] : 0;
        __syncthreads();
        s[t] += a;
        __syncthreads();
    }
    int excl = s[t] - tot;
    bucketBase[t] = excl;
    if (t == NB - 1) bucketBase[NB] = s[NB - 1];
    int run = excl;
    for (int blk = 0; blk < NB; ++blk) {
        blkbase[blk * NB + t] = run;
        run += blkcnt[blk * NB + t];
    }
}

// ---- 3. bin edges into buckets (private contiguous runs) ----
__global__ __launch_bounds__(256) void k_bin(const void* __restrict__ ei,
                                             const int* __restrict__ blkbase,
                                             int2* __restrict__ binned,
                                             const int* __restrict__ flags) {
    __shared__ int bb[NB];
    __shared__ int rank[NB];
    int t = threadIdx.x, blk = blockIdx.x;
    int f = flags[1];
    for (int j = t; j < NB; j += 256) { bb[j] = blkbase[blk * NB + j]; rank[j] = 0; }
    __syncthreads();
    int lo = blk * CHUNK, hi = lo + CHUNK;
    for (int e = lo + t; e < hi; e += 256) {
        int s = idx_at(ei, e, f);
        int d = idx_at(ei, (long)N_EDGES + e, f);
        int b = d / NPB;
        int r = atomicAdd(&rank[b], 1);
        binned[bb[b] + r] = make_int2(s, d);
    }
}

// ---- 4. per-bucket CSR in LDS, coalesced flush ----
__global__ __launch_bounds__(256) void k_csr(const int2* __restrict__ binned,
                                             const int* __restrict__ bucketBase,
                                             int* __restrict__ rowptr,
                                             int* __restrict__ csr) {
    __shared__ int cnt[400];
    __shared__ int sc[400];
    __shared__ int sh[256];
    __shared__ int stage[STAGE];  // 30 KB
    int t = threadIdx.x, b = blockIdx.x;
    int nodeLo = b * NPB;
    int nC = N_NODES - nodeLo; if (nC > NPB) nC = NPB;
    int eBase = bucketBase[b], eEnd = bucketBase[b + 1];

    for (int j = t; j < 400; j += 256) cnt[j] = 0;
    __syncthreads();
    for (int i = eBase + t; i < eEnd; i += 256)
        atomicAdd(&cnt[binned[i].y - nodeLo], 1);
    __syncthreads();
    // exclusive scan of cnt[0..400) -> sc
    int base = t * 2;
    int v0 = (base < 400) ? cnt[base] : 0;
    int v1 = (base + 1 < 400) ? cnt[base + 1] : 0;
    int ssum = v0 + v1;
    sh[t] = ssum; __syncthreads();
    for (int off = 1; off < 256; off <<= 1) {
        int a = (t >= off) ? sh[t - off] : 0;
        __syncthreads();
        sh[t] += a;
        __syncthreads();
    }
    int pre = sh[t] - ssum;
    if (base < 400) sc[base] = pre;
    if (base + 1 < 400) sc[base + 1] = pre + v0;
    __syncthreads();
    for (int j = t; j < nC; j += 256) rowptr[nodeLo + j] = eBase + sc[j];
    if (b == NB - 1) {
        if (t == 0) rowptr[N_NODES] = eEnd;
        if (t < 8) csr[N_EDGES + t] = 0;   // pad for unrolled agg reads
    }
    for (int j = t; j < 400; j += 256) cnt[j] = 0;  // reuse as rank
    __syncthreads();
    for (int i = eBase + t; i < eEnd; i += 256) {
        int2 p = binned[i];
        int loc = p.y - nodeLo;
        int pos = sc[loc] + atomicAdd(&cnt[loc], 1);
        if (pos < STAGE) stage[pos] = p.x;
        else csr[eBase + pos] = p.x;   // statistical never
    }
    __syncthreads();
    int eCnt = eEnd - eBase; if (eCnt > STAGE) eCnt = STAGE;
    for (int j = t; j < eCnt; j += 256) csr[eBase + j] = stage[j];
}

// ---- 5. mean aggregation: wave per node, 8 loads in flight, scalar csr ----
__global__ __launch_bounds__(256) void k_agg(const ushort* __restrict__ xa,
                                             const ushort* __restrict__ xb,
                                             const int* __restrict__ rowptr,
                                             const int* __restrict__ csr,
                                             ushort* __restrict__ mout,
                                             const int* __restrict__ flags,
                                             int use_sel) {
    int wid = blockIdx.x * 4 + (threadIdx.x >> 6);
    int lane = threadIdx.x & 63;
    if (wid >= N_NODES) return;
    const ushort* xin = use_sel ? (flags[0] ? xa : xb) : xa;
    const unsigned int* xr = (const unsigned int*)xin;
    int beg = __builtin_amdgcn_readfirstlane(rowptr[wid]);
    int end = __builtin_amdgcn_readfirstlane(rowptr[wid + 1]);
    float a0 = 0.f, a1 = 0.f;
    for (int j = beg; j < end; j += 8) {
        unsigned int p[8];
#pragma unroll
        for (int i = 0; i < 8; ++i) {
            int jj = j + i;
            if (jj > end - 1) jj = end - 1;         // clamp: dup load hits cache
            int idx = __builtin_amdgcn_readfirstlane(csr[jj]);
            p[i] = xr[(long)idx * 64 + lane];
        }
#pragma unroll
        for (int i = 0; i < 8; ++i) {
            unsigned int q = (j + i < end) ? p[i] : 0u;
            a0 += blo(q); a1 += bhi(q);
        }
    }
    int deg = end - beg;
    float scale = (deg > 0) ? 1.f / (float)deg : 0.f;
    unsigned int packed = ((unsigned int)f2b(a1 * scale) << 16) | (unsigned int)f2b(a0 * scale);
    ((unsigned int*)mout)[wid * 64 + lane] = packed;
}

// ---- 6. fused SAGE linear: out = relu([A0|A1] @ [Wl;Wr]^T + b), all bf16 ----
__global__ __launch_bounds__(256) void k_gemm(const ushort* __restrict__ A0,
                                              const ushort* __restrict__ A1a,
                                              const ushort* __restrict__ A1b,
                                              const ushort* __restrict__ Wl,
                                              const ushort* __restrict__ Wr,
                                              const ushort* __restrict__ bias,
                                              ushort* __restrict__ out,
                                              const int* __restrict__ flags,
                                              int use_sel) {
    __shared__ short Ws[4096 * 8];  // 64 KiB fragment-interleaved weights
    int t = threadIdx.x;
    const ushort* A1 = use_sel ? (flags[0] ? A1a : A1b) : A1a;
#pragma unroll
    for (int i = 0; i < 16; ++i) {
        int f = i * 256 + t;
        int lane = f & 63, kk = (f >> 6) & 7, tile = f >> 9;
        int o = tile * 16 + (lane & 15);
        int k0 = kk * 32 + ((lane >> 4) * 8);
        const ushort* wsrc = (k0 < 128) ? (Wl + o * 128 + k0)
                                        : (Wr + o * 128 + (k0 - 128));
        *(short8*)&Ws[f * 8] = *(const short8*)wsrc;
    }
    __syncthreads();

    int wid = t >> 6, lane = t & 63;
    long nbase = (long)blockIdx.x * 64 + (long)wid * 16;
    int arow = (int)nbase + (lane & 15);
    if (arow >= N_NODES) arow = N_NODES - 1;   // clamp (stores guarded)
    int kq = (lane >> 4) * 8;

    short8 afrag[8];
#pragma unroll
    for (int kk = 0; kk < 8; ++kk) {
        int k0 = kk * 32 + kq;
        afrag[kk] = (k0 < 128)
            ? *(const short8*)(A0 + (long)arow * 128 + k0)
            : *(const short8*)(A1 + (long)arow * 128 + (k0 - 128));
    }

#pragma unroll
    for (int tile = 0; tile < 8; ++tile) {
        f32x4 acc = {0.f, 0.f, 0.f, 0.f};
#pragma unroll
        for (int kk = 0; kk < 8; ++kk) {
            short8 bfrag = *(short8*)&Ws[((tile * 8 + kk) * 64 + lane) * 8];
            acc = __builtin_amdgcn_mfma_f32_16x16x32_bf16(afrag[kk], bfrag, acc, 0, 0, 0);
        }
        int o = tile * 16 + (lane & 15);
        float bo = b2f(bias[o]);
#pragma unroll
        for (int r = 0; r < 4; ++r) {
            long node = nbase + (lane >> 4) * 4 + r;
            if (node < N_NODES) {
                float v = acc[r] + bo;
                v = v > 0.f ? v : 0.f;
                out[node * 128 + o] = f2b(v);
            }
        }
    }
}

// ---- 7. fused global mean pool + classifier + log_softmax ----
__global__ __launch_bounds__(128) void k_pool_cls(const ushort* __restrict__ h2,
                                                  const void* __restrict__ batch,
                                                  const void* __restrict__ Wf,
                                                  const void* __restrict__ bfv,
                                                  void* __restrict__ outp,
                                                  const int* __restrict__ flags) {
    int g = blockIdx.x, t = threadIdx.x;  // 128 threads
    bool f32 = (flags[0] == 0);
    int b64 = flags[2];
    __shared__ int rng[2];
    __shared__ float gv[128];
    __shared__ float lg[10];
    if (t < 2) {
        int v = g + t, lo = 0, hi = N_NODES;
        while (lo < hi) {
            int mid = (lo + hi) >> 1;
            if (idx_at(batch, mid, b64) < v) lo = mid + 1; else hi = mid;
        }
        rng[t] = lo;
    }
    __syncthreads();
    int lo = rng[0], hi = rng[1];
    float acc = 0.f;
    for (int n = lo; n < hi; ++n) acc += b2f(h2[(long)n * 128 + t]);
    float c = (hi > lo) ? (float)(hi - lo) : 1.f;
    gv[t] = acc / c;
    __syncthreads();
    if (t < 10) {
        float s = f32 ? ((const float*)bfv)[t] : b2f(((const ushort*)bfv)[t]);
        for (int k = 0; k < 128; ++k) {
            float wv = f32 ? ((const float*)Wf)[t * 128 + k] : b2f(((const ushort*)Wf)[t * 128 + k]);
            s += gv[k] * wv;
        }
        lg[t] = s;
    }
    __syncthreads();
    if (t == 0) {
        float mx = lg[0];
        for (int i = 1; i < 10; ++i) mx = fmaxf(mx, lg[i]);
        float se = 0.f;
        for (int i = 0; i < 10; ++i) se += expf(lg[i] - mx);
        float lse = mx + logf(se);
        for (int i = 0; i < 10; ++i) {
            float v = lg[i] - lse;
            if (f32) ((float*)outp)[g * 10 + i] = v;
            else     ((ushort*)outp)[g * 10 + i] = f2b(v);
        }
    }
}

extern "C" void kernel_launch(void* const* d_in, const int* in_sizes, int n_in,
                              void* d_out, int out_size, void* d_ws, size_t ws_size,
                              hipStream_t stream) {
    const void* x     = d_in[0];
    const void* ei    = d_in[1];
    const void* batch = d_in[2];
    const void* W1l = d_in[3];
    const void* b1  = d_in[4];
    const void* W1r = d_in[5];
    const void* W2l = d_in[6];
    const void* b2  = d_in[7];
    const void* W2r = d_in[8];
    const void* Wf  = d_in[9];
    const void* bf_ = d_in[10];

    // workspace layout (aliased by lifetime; high-water 83,732,736 B)
    char* w = (char*)d_ws;
    int* flags      = (int*)(w + 0);              // 3 ints
    int* rowptr     = (int*)(w + 640);            // 100001 ints
    ushort* wbf     = (ushort*)(w + 400768);      // 65792 shorts
    int* csr        = (int*)(w + 532480);         // 1600008 ints
    ushort* xbf     = (ushort*)(w + 6932736);     // 12.8M bf16
    ushort* mbuf    = (ushort*)(w + 32532736);    // 12.8M bf16 (CSR-era aliases below)
    int* bucketBase = (int*)(w + 32532736);       //   257 ints   (dead after k_csr)
    int* blkcnt     = (int*)(w + 32534016);       //   256*256    (dead after k_bscan)
    int* blkbase    = (int*)(w + 32796160);       //   256*256    (dead after k_bin)
    ushort* h1      = (ushort*)(w + 58132736);    // 12.8M bf16
    int2* binned    = (int2*)(w + 58132736);      //   1.6M int2 (dead before h1 written)
    ushort* h2      = mbuf;                       // gemm2 is wave-row-exclusive

    dim3 blk256(256), blkNB(NB), blk128(128);

    k_detect<<<1, blk256, 0, stream>>>((const unsigned int*)x, (const unsigned int*)ei,
                                       (const int*)batch, flags);
    k_prep<<<NB + 2048 + 257, blk256, 0, stream>>>(ei, (const float4*)x, xbf,
                                                   W1l, W1r, W2l, W2r, b1, b2,
                                                   wbf, blkcnt, flags);
    k_bscan<<<1, blkNB, 0, stream>>>(blkcnt, bucketBase, blkbase);
    k_bin<<<NB, blk256, 0, stream>>>(ei, blkbase, binned, flags);
    k_csr<<<NB, blk256, 0, stream>>>(binned, bucketBase, rowptr, csr);

    int agrid = (N_NODES + 3) / 4;               // 25000 (wave per node)
    int ggrid = (N_NODES + 63) / 64;             // 1563

    // layer 1
    k_agg<<<agrid, blk256, 0, stream>>>((const ushort*)x, xbf, rowptr, csr, mbuf, flags, 1);
    k_gemm<<<ggrid, blk256, 0, stream>>>(mbuf, (const ushort*)x, xbf,
                                         wbf + 0, wbf + 16384, wbf + 65536, h1, flags, 1);
    // layer 2
    k_agg<<<agrid, blk256, 0, stream>>>(h1, h1, rowptr, csr, mbuf, flags, 0);
    k_gemm<<<ggrid, blk256, 0, stream>>>(mbuf, h1, h1,
                                         wbf + 32768, wbf + 49152, wbf + 65664, h2, flags, 0);
    // pool + classify
    k_pool_cls<<<N_GRAPHS, blk128, 0, stream>>>(h2, batch, Wf, bf_, d_out, flags);
}

// Round 5
// 373.465 us; speedup vs baseline: 1.8812x; 1.1410x over previous
//
#include <hip/hip_runtime.h>
#include <hip/hip_bf16.h>

#define N_NODES 100000
#define N_EDGES 1600000
#define N_GRAPHS 512
#define NB 256                 // coarse dst-buckets
#define NPB 391                // nodes per bucket (256*391 = 100096 >= 100000)
#define CHUNK 6250             // edges per binning block (256*6250 = 1.6M exact)
#define STAGE 7680             // LDS csr staging per bucket (mean 6250, sd ~79)

typedef __attribute__((ext_vector_type(8))) short short8;
typedef __attribute__((ext_vector_type(4))) float f32x4;

// ---- bf16 helpers ----
__device__ __forceinline__ float b2f(ushort u) {
    union { unsigned int i; float f; } c; c.i = ((unsigned int)u) << 16; return c.f;
}
__device__ __forceinline__ float blo(unsigned int u) {
    union { unsigned int i; float f; } c; c.i = u << 16; return c.f;
}
__device__ __forceinline__ float bhi(unsigned int u) {
    union { unsigned int i; float f; } c; c.i = u & 0xffff0000u; return c.f;
}
__device__ __forceinline__ ushort f2b(float f) {  // round-to-nearest-even
    union { float f; unsigned int i; } c; c.f = f;
    unsigned int r = (c.i + 0x7fffu + ((c.i >> 16) & 1u)) >> 16;
    return (ushort)r;
}
__device__ __forceinline__ int idx_at(const void* p, long i, int f) {
    return f ? (int)((const long long*)p)[i] : ((const int*)p)[i];
}

// ---- 0. dtype detection ----
// flags[0]: 1 = floats bf16, 0 = fp32 ; flags[1]: edge int64? ; flags[2]: batch int64?
__global__ __launch_bounds__(256) void k_detect(const unsigned int* __restrict__ xw,
                                                const unsigned int* __restrict__ ew,
                                                const int* __restrict__ bw,
                                                int* __restrict__ flags) {
    __shared__ int cf, ce, cb;
    int t = threadIdx.x;
    if (t == 0) { cf = 0; ce = 0; cb = 0; }
    __syncthreads();
    unsigned int w = xw[t];
    unsigned int e = (w >> 7) & 0xffu;
    if (e >= 110u && e <= 130u) atomicAdd(&cf, 1);
    if (t < 128) {
        if (ew[2 * t + 1] != 0u) atomicAdd(&ce, 1);
        if (bw[99001 + 2 * t] != 0) atomicAdd(&cb, 1);
    }
    __syncthreads();
    if (t == 0) {
        flags[0] = (cf >= 128) ? 1 : 0;
        flags[1] = (ce == 0) ? 1 : 0;
        flags[2] = (cb == 0) ? 1 : 0;
    }
}

// ---- 1. fused prep: [0,NB) bucket-hist | [NB,NB+2048) cvt_x | rest cvt_w ----
__global__ __launch_bounds__(256) void k_prep(const void* __restrict__ ei,
                                              const float4* __restrict__ xf,
                                              ushort* __restrict__ xbf,
                                              const void* W1l, const void* W1r,
                                              const void* W2l, const void* W2r,
                                              const void* b1,  const void* b2,
                                              ushort* __restrict__ wbf,
                                              int* __restrict__ blkcnt,
                                              const int* __restrict__ flags) {
    int b = blockIdx.x, t = threadIdx.x;
    if (b < NB) {
        __shared__ int h[NB];
        int f = flags[1];
        for (int j = t; j < NB; j += 256) h[j] = 0;
        __syncthreads();
        int lo = b * CHUNK, hi = lo + CHUNK;
        for (int e = lo + t; e < hi; e += 256) {
            int d = idx_at(ei, (long)N_EDGES + e, f);
            atomicAdd(&h[d / NPB], 1);
        }
        __syncthreads();
        if (t < NB) blkcnt[b * NB + t] = h[t];
    } else if (b < NB + 2048) {
        if (flags[0] != 0) return;   // already bf16
        int vb = b - NB;
        long n4 = (long)N_NODES * 128 / 4;  // 3.2M float4
        for (long i = (long)vb * 256 + t; i < n4; i += 2048L * 256) {
            float4 v = xf[i];
            ushort* o = xbf + i * 4;
            o[0] = f2b(v.x); o[1] = f2b(v.y); o[2] = f2b(v.z); o[3] = f2b(v.w);
        }
    } else {
        // weights+biases -> bf16: W1l@0 W1r@16384 W2l@32768 W2r@49152 b1@65536 b2@65664
        int idx = (b - NB - 2048) * 256 + t;
        if (idx >= 65792) return;
        const void* src; int off;
        if      (idx < 16384) { src = W1l; off = idx; }
        else if (idx < 32768) { src = W1r; off = idx - 16384; }
        else if (idx < 49152) { src = W2l; off = idx - 32768; }
        else if (idx < 65536) { src = W2r; off = idx - 49152; }
        else if (idx < 65664) { src = b1;  off = idx - 65536; }
        else                  { src = b2;  off = idx - 65664; }
        wbf[idx] = (flags[0] != 0) ? ((const ushort*)src)[off]
                                   : f2b(((const float*)src)[off]);
    }
}

// ---- 2. scan: bucketBase + per-(block,bucket) bases (1 block, NB threads) ----
__global__ __launch_bounds__(NB) void k_bscan(const int* __restrict__ blkcnt,
                                              int* __restrict__ bucketBase,
                                              int* __restrict__ blkbase) {
    __shared__ int s[NB];
    int t = threadIdx.x;
    int tot = 0;
    for (int blk = 0; blk < NB; ++blk) tot += blkcnt[blk * NB + t];
    s[t] = tot; __syncthreads();
    for (int off = 1; off < NB; off <<= 1) {
        int a = (t >= off) ? s[t - off] : 0;
        __syncthreads();
        s[t] += a;
        __syncthreads();
    }
    int excl = s[t] - tot;
    bucketBase[t] = excl;
    if (t == NB - 1) bucketBase[NB] = s[NB - 1];
    int run = excl;
    for (int blk = 0; blk < NB; ++blk) {
        blkbase[blk * NB + t] = run;
        run += blkcnt[blk * NB + t];
    }
}

// ---- 3. bin edges into buckets (private contiguous runs) ----
__global__ __launch_bounds__(256) void k_bin(const void* __restrict__ ei,
                                             const int* __restrict__ blkbase,
                                             int2* __restrict__ binned,
                                             const int* __restrict__ flags) {
    __shared__ int bb[NB];
    __shared__ int rank[NB];
    int t = threadIdx.x, blk = blockIdx.x;
    int f = flags[1];
    for (int j = t; j < NB; j += 256) { bb[j] = blkbase[blk * NB + j]; rank[j] = 0; }
    __syncthreads();
    int lo = blk * CHUNK, hi = lo + CHUNK;
    for (int e = lo + t; e < hi; e += 256) {
        int s = idx_at(ei, e, f);
        int d = idx_at(ei, (long)N_EDGES + e, f);
        int b = d / NPB;
        int r = atomicAdd(&rank[b], 1);
        binned[bb[b] + r] = make_int2(s, d);
    }
}

// ---- 4. per-bucket CSR in LDS, coalesced flush ----
__global__ __launch_bounds__(256) void k_csr(const int2* __restrict__ binned,
                                             const int* __restrict__ bucketBase,
                                             int* __restrict__ rowptr,
                                             int* __restrict__ csr) {
    __shared__ int cnt[400];
    __shared__ int sc[400];
    __shared__ int sh[256];
    __shared__ int stage[STAGE];  // 30 KB
    int t = threadIdx.x, b = blockIdx.x;
    int nodeLo = b * NPB;
    int nC = N_NODES - nodeLo; if (nC > NPB) nC = NPB;
    int eBase = bucketBase[b], eEnd = bucketBase[b + 1];

    for (int j = t; j < 400; j += 256) cnt[j] = 0;
    __syncthreads();
    for (int i = eBase + t; i < eEnd; i += 256)
        atomicAdd(&cnt[binned[i].y - nodeLo], 1);
    __syncthreads();
    int base = t * 2;
    int v0 = (base < 400) ? cnt[base] : 0;
    int v1 = (base + 1 < 400) ? cnt[base + 1] : 0;
    int ssum = v0 + v1;
    sh[t] = ssum; __syncthreads();
    for (int off = 1; off < 256; off <<= 1) {
        int a = (t >= off) ? sh[t - off] : 0;
        __syncthreads();
        sh[t] += a;
        __syncthreads();
    }
    int pre = sh[t] - ssum;
    if (base < 400) sc[base] = pre;
    if (base + 1 < 400) sc[base + 1] = pre + v0;
    __syncthreads();
    for (int j = t; j < nC; j += 256) rowptr[nodeLo + j] = eBase + sc[j];
    if (b == NB - 1) {
        if (t == 0) rowptr[N_NODES] = eEnd;
        if (t < 8) csr[N_EDGES + t] = 0;   // pad for unrolled agg reads
    }
    for (int j = t; j < 400; j += 256) cnt[j] = 0;  // reuse as rank
    __syncthreads();
    for (int i = eBase + t; i < eEnd; i += 256) {
        int2 p = binned[i];
        int loc = p.y - nodeLo;
        int pos = sc[loc] + atomicAdd(&cnt[loc], 1);
        if (pos < STAGE) stage[pos] = p.x;
        else csr[eBase + pos] = p.x;   // statistical never
    }
    __syncthreads();
    int eCnt = eEnd - eBase; if (eCnt > STAGE) eCnt = STAGE;
    for (int j = t; j < eCnt; j += 256) csr[eBase + j] = stage[j];
}

// ---- 5. mean aggregation: wave per node, 8 loads in flight, scalar csr ----
__global__ __launch_bounds__(256) void k_agg(const ushort* __restrict__ xa,
                                             const ushort* __restrict__ xb,
                                             const int* __restrict__ rowptr,
                                             const int* __restrict__ csr,
                                             ushort* __restrict__ mout,
                                             const int* __restrict__ flags,
                                             int use_sel) {
    int wid = blockIdx.x * 4 + (threadIdx.x >> 6);
    int lane = threadIdx.x & 63;
    if (wid >= N_NODES) return;
    const ushort* xin = use_sel ? (flags[0] ? xa : xb) : xa;
    const unsigned int* xr = (const unsigned int*)xin;
    int beg = __builtin_amdgcn_readfirstlane(rowptr[wid]);
    int end = __builtin_amdgcn_readfirstlane(rowptr[wid + 1]);
    float a0 = 0.f, a1 = 0.f;
    for (int j = beg; j < end; j += 8) {
        unsigned int p[8];
#pragma unroll
        for (int i = 0; i < 8; ++i) {
            int jj = j + i;
            if (jj > end - 1) jj = end - 1;         // clamp: dup load hits cache
            int idx = __builtin_amdgcn_readfirstlane(csr[jj]);
            p[i] = xr[(long)idx * 64 + lane];
        }
#pragma unroll
        for (int i = 0; i < 8; ++i) {
            unsigned int q = (j + i < end) ? p[i] : 0u;
            a0 += blo(q); a1 += bhi(q);
        }
    }
    int deg = end - beg;
    float scale = (deg > 0) ? 1.f / (float)deg : 0.f;
    unsigned int packed = ((unsigned int)f2b(a1 * scale) << 16) | (unsigned int)f2b(a0 * scale);
    ((unsigned int*)mout)[wid * 64 + lane] = packed;
}

// ---- 6. fused SAGE linear: out = relu([A0|A1] @ [Wl;Wr]^T + b), all bf16 ----
__global__ __launch_bounds__(256) void k_gemm(const ushort* __restrict__ A0,
                                              const ushort* __restrict__ A1a,
                                              const ushort* __restrict__ A1b,
                                              const ushort* __restrict__ Wl,
                                              const ushort* __restrict__ Wr,
                                              const ushort* __restrict__ bias,
                                              ushort* __restrict__ out,
                                              const int* __restrict__ flags,
                                              int use_sel) {
    __shared__ short Ws[4096 * 8];  // 64 KiB fragment-interleaved weights
    int t = threadIdx.x;
    const ushort* A1 = use_sel ? (flags[0] ? A1a : A1b) : A1a;
#pragma unroll
    for (int i = 0; i < 16; ++i) {
        int f = i * 256 + t;
        int lane = f & 63, kk = (f >> 6) & 7, tile = f >> 9;
        int o = tile * 16 + (lane & 15);
        int k0 = kk * 32 + ((lane >> 4) * 8);
        const ushort* wsrc = (k0 < 128) ? (Wl + o * 128 + k0)
                                        : (Wr + o * 128 + (k0 - 128));
        *(short8*)&Ws[f * 8] = *(const short8*)wsrc;
    }
    __syncthreads();

    int wid = t >> 6, lane = t & 63;
    long nbase = (long)blockIdx.x * 64 + (long)wid * 16;
    int arow = (int)nbase + (lane & 15);
    if (arow >= N_NODES) arow = N_NODES - 1;   // clamp (stores guarded)
    int kq = (lane >> 4) * 8;

    short8 afrag[8];
#pragma unroll
    for (int kk = 0; kk < 8; ++kk) {
        int k0 = kk * 32 + kq;
        afrag[kk] = (k0 < 128)
            ? *(const short8*)(A0 + (long)arow * 128 + k0)
            : *(const short8*)(A1 + (long)arow * 128 + (k0 - 128));
    }

#pragma unroll
    for (int tile = 0; tile < 8; ++tile) {
        f32x4 acc = {0.f, 0.f, 0.f, 0.f};
#pragma unroll
        for (int kk = 0; kk < 8; ++kk) {
            short8 bfrag = *(short8*)&Ws[((tile * 8 + kk) * 64 + lane) * 8];
            acc = __builtin_amdgcn_mfma_f32_16x16x32_bf16(afrag[kk], bfrag, acc, 0, 0, 0);
        }
        int o = tile * 16 + (lane & 15);
        float bo = b2f(bias[o]);
#pragma unroll
        for (int r = 0; r < 4; ++r) {
            long node = nbase + (lane >> 4) * 4 + r;
            if (node < N_NODES) {
                float v = acc[r] + bo;
                v = v > 0.f ? v : 0.f;
                out[node * 128 + o] = f2b(v);
            }
        }
    }
}

// ---- 7. fused global mean pool + classifier + log_softmax ----
// 256 threads: 64 lanes cover 128 feats (uint bf16x2); 4 waves split node range; unroll 8.
__global__ __launch_bounds__(256) void k_pool_cls(const ushort* __restrict__ h2,
                                                  const void* __restrict__ batch,
                                                  const void* __restrict__ Wf,
                                                  const void* __restrict__ bfv,
                                                  void* __restrict__ outp,
                                                  const int* __restrict__ flags) {
    int g = blockIdx.x, t = threadIdx.x;
    int wid = t >> 6, lane = t & 63;
    bool f32 = (flags[0] == 0);
    int b64 = flags[2];
    __shared__ int rng[2];
    __shared__ float redA[4][64];
    __shared__ float redB[4][64];
    __shared__ float gv[128];
    __shared__ float lg[10];
    if (t < 2) {
        int v = g + t, lo = 0, hi = N_NODES;
        while (lo < hi) {
            int mid = (lo + hi) >> 1;
            if (idx_at(batch, mid, b64) < v) lo = mid + 1; else hi = mid;
        }
        rng[t] = lo;
    }
    __syncthreads();
    int lo = rng[0], hi = rng[1];
    const unsigned int* xr = (const unsigned int*)h2;
    float a0 = 0.f, a1 = 0.f;
    int n = lo + wid;
    // 8 independent loads in flight per wave (nodes n, n+4, ..., n+28)
    for (; n + 28 < hi; n += 32) {
        unsigned int p[8];
#pragma unroll
        for (int i = 0; i < 8; ++i) p[i] = xr[(long)(n + i * 4) * 64 + lane];
#pragma unroll
        for (int i = 0; i < 8; ++i) { a0 += blo(p[i]); a1 += bhi(p[i]); }
    }
    for (; n < hi; n += 4) {
        unsigned int q = xr[(long)n * 64 + lane];
        a0 += blo(q); a1 += bhi(q);
    }
    redA[wid][lane] = a0;
    redB[wid][lane] = a1;
    __syncthreads();
    if (wid == 0) {
        float s0 = redA[0][lane] + redA[1][lane] + redA[2][lane] + redA[3][lane];
        float s1 = redB[0][lane] + redB[1][lane] + redB[2][lane] + redB[3][lane];
        float c = (hi > lo) ? (float)(hi - lo) : 1.f;
        gv[lane * 2]     = s0 / c;
        gv[lane * 2 + 1] = s1 / c;
    }
    __syncthreads();
    if (t < 10) {
        float s = f32 ? ((const float*)bfv)[t] : b2f(((const ushort*)bfv)[t]);
        for (int k = 0; k < 128; ++k) {
            float wv = f32 ? ((const float*)Wf)[t * 128 + k] : b2f(((const ushort*)Wf)[t * 128 + k]);
            s += gv[k] * wv;
        }
        lg[t] = s;
    }
    __syncthreads();
    if (t == 0) {
        float mx = lg[0];
        for (int i = 1; i < 10; ++i) mx = fmaxf(mx, lg[i]);
        float se = 0.f;
        for (int i = 0; i < 10; ++i) se += expf(lg[i] - mx);
        float lse = mx + logf(se);
        for (int i = 0; i < 10; ++i) {
            float v = lg[i] - lse;
            if (f32) ((float*)outp)[g * 10 + i] = v;
            else     ((ushort*)outp)[g * 10 + i] = f2b(v);
        }
    }
}

extern "C" void kernel_launch(void* const* d_in, const int* in_sizes, int n_in,
                              void* d_out, int out_size, void* d_ws, size_t ws_size,
                              hipStream_t stream) {
    const void* x     = d_in[0];
    const void* ei    = d_in[1];
    const void* batch = d_in[2];
    const void* W1l = d_in[3];
    const void* b1  = d_in[4];
    const void* W1r = d_in[5];
    const void* W2l = d_in[6];
    const void* b2  = d_in[7];
    const void* W2r = d_in[8];
    const void* Wf  = d_in[9];
    const void* bf_ = d_in[10];

    // workspace layout (aliased by lifetime; high-water 83,732,736 B)
    char* w = (char*)d_ws;
    int* flags      = (int*)(w + 0);              // 3 ints
    int* rowptr     = (int*)(w + 640);            // 100001 ints
    ushort* wbf     = (ushort*)(w + 400768);      // 65792 shorts
    int* csr        = (int*)(w + 532480);         // 1600008 ints
    ushort* xbf     = (ushort*)(w + 6932736);     // 12.8M bf16
    ushort* mbuf    = (ushort*)(w + 32532736);    // 12.8M bf16 (CSR-era aliases below)
    int* bucketBase = (int*)(w + 32532736);       //   257 ints   (dead after k_csr)
    int* blkcnt     = (int*)(w + 32534016);       //   256*256    (dead after k_bscan)
    int* blkbase    = (int*)(w + 32796160);       //   256*256    (dead after k_bin)
    ushort* h1      = (ushort*)(w + 58132736);    // 12.8M bf16
    int2* binned    = (int2*)(w + 58132736);      //   1.6M int2 (dead before h1 written)
    ushort* h2      = mbuf;                       // gemm2 is wave-row-exclusive

    dim3 blk256(256), blkNB(NB);

    k_detect<<<1, blk256, 0, stream>>>((const unsigned int*)x, (const unsigned int*)ei,
                                       (const int*)batch, flags);
    k_prep<<<NB + 2048 + 257, blk256, 0, stream>>>(ei, (const float4*)x, xbf,
                                                   W1l, W1r, W2l, W2r, b1, b2,
                                                   wbf, blkcnt, flags);
    k_bscan<<<1, blkNB, 0, stream>>>(blkcnt, bucketBase, blkbase);
    k_bin<<<NB, blk256, 0, stream>>>(ei, blkbase, binned, flags);
    k_csr<<<NB, blk256, 0, stream>>>(binned, bucketBase, rowptr, csr);

    int agrid = (N_NODES + 3) / 4;               // 25000 (wave per node)
    int ggrid = (N_NODES + 63) / 64;             // 1563

    // layer 1
    k_agg<<<agrid, blk256, 0, stream>>>((const ushort*)x, xbf, rowptr, csr, mbuf, flags, 1);
    k_gemm<<<ggrid, blk256, 0, stream>>>(mbuf, (const ushort*)x, xbf,
                                         wbf + 0, wbf + 16384, wbf + 65536, h1, flags, 1);
    // layer 2
    k_agg<<<agrid, blk256, 0, stream>>>(h1, h1, rowptr, csr, mbuf, flags, 0);
    k_gemm<<<ggrid, blk256, 0, stream>>>(mbuf, h1, h1,
                                         wbf + 32768, wbf + 49152, wbf + 65664, h2, flags, 0);
    // pool + classify
    k_pool_cls<<<N_GRAPHS, blk256, 0, stream>>>(h2, batch, Wf, bf_, d_out, flags);
}

// Round 6
// 357.322 us; speedup vs baseline: 1.9662x; 1.0452x over previous
//
#include <hip/hip_runtime.h>
#include <hip/hip_bf16.h>

#define N_NODES 100000
#define N_EDGES 1600000
#define N_GRAPHS 512
#define NB 256                 // coarse dst-buckets
#define NPB 391                // nodes per bucket (256*391 = 100096 >= 100000)
#define CHUNK 6250             // edges per binning block (256*6250 = 1.6M exact)
#define STAGE 7680             // LDS csr staging per bucket (mean 6250, sd ~79)

typedef __attribute__((ext_vector_type(8))) short short8;
typedef __attribute__((ext_vector_type(4))) float f32x4;
typedef __attribute__((ext_vector_type(2))) float f32x2;

// ---- bf16 helpers ----
__device__ __forceinline__ float b2f(ushort u) {
    union { unsigned int i; float f; } c; c.i = ((unsigned int)u) << 16; return c.f;
}
__device__ __forceinline__ float blo(unsigned int u) {
    union { unsigned int i; float f; } c; c.i = u << 16; return c.f;
}
__device__ __forceinline__ float bhi(unsigned int u) {
    union { unsigned int i; float f; } c; c.i = u & 0xffff0000u; return c.f;
}
__device__ __forceinline__ ushort f2b(float f) {  // round-to-nearest-even
    union { float f; unsigned int i; } c; c.f = f;
    unsigned int r = (c.i + 0x7fffu + ((c.i >> 16) & 1u)) >> 16;
    return (ushort)r;
}
__device__ __forceinline__ int idx_at(const void* p, long i, int f) {
    return f ? (int)((const long long*)p)[i] : ((const int*)p)[i];
}

// ---- 0. dtype detection ----
// flags[0]: 1 = floats bf16, 0 = fp32 ; flags[1]: edge int64? ; flags[2]: batch int64?
__global__ __launch_bounds__(256) void k_detect(const unsigned int* __restrict__ xw,
                                                const unsigned int* __restrict__ ew,
                                                const int* __restrict__ bw,
                                                int* __restrict__ flags) {
    __shared__ int cf, ce, cb;
    int t = threadIdx.x;
    if (t == 0) { cf = 0; ce = 0; cb = 0; }
    __syncthreads();
    unsigned int w = xw[t];
    unsigned int e = (w >> 7) & 0xffu;
    if (e >= 110u && e <= 130u) atomicAdd(&cf, 1);
    if (t < 128) {
        if (ew[2 * t + 1] != 0u) atomicAdd(&ce, 1);
        if (bw[99001 + 2 * t] != 0) atomicAdd(&cb, 1);
    }
    __syncthreads();
    if (t == 0) {
        flags[0] = (cf >= 128) ? 1 : 0;
        flags[1] = (ce == 0) ? 1 : 0;
        flags[2] = (cb == 0) ? 1 : 0;
    }
}

// ---- 1. fused prep: [0,NB) bucket-hist | [NB,NB+2048) cvt x -> xbf + xf8 | rest cvt_w ----
__global__ __launch_bounds__(256) void k_prep(const void* __restrict__ ei,
                                              const void* __restrict__ x,
                                              ushort* __restrict__ xbf,
                                              unsigned int* __restrict__ xf8,
                                              const void* W1l, const void* W1r,
                                              const void* W2l, const void* W2r,
                                              const void* b1,  const void* b2,
                                              ushort* __restrict__ wbf,
                                              int* __restrict__ blkcnt,
                                              const int* __restrict__ flags) {
    int b = blockIdx.x, t = threadIdx.x;
    if (b < NB) {
        __shared__ int h[NB];
        int f = flags[1];
        for (int j = t; j < NB; j += 256) h[j] = 0;
        __syncthreads();
        int lo = b * CHUNK, hi = lo + CHUNK;
        for (int e = lo + t; e < hi; e += 256) {
            int d = idx_at(ei, (long)N_EDGES + e, f);
            atomicAdd(&h[d / NPB], 1);
        }
        __syncthreads();
        if (t < NB) blkcnt[b * NB + t] = h[t];
    } else if (b < NB + 2048) {
        bool f32src = (flags[0] == 0);
        int vb = b - NB;
        const long nG = (long)N_NODES * 128 / 4;   // 3.2M groups of 4 feats
        for (long g = (long)vb * 256 + t; g < nG; g += 2048L * 256) {
            float v0, v1, v2, v3;
            if (f32src) {
                float4 vv = ((const float4*)x)[g];
                v0 = vv.x; v1 = vv.y; v2 = vv.z; v3 = vv.w;
                unsigned int lo = (unsigned int)f2b(v0) | ((unsigned int)f2b(v1) << 16);
                unsigned int hi = (unsigned int)f2b(v2) | ((unsigned int)f2b(v3) << 16);
                ((uint2*)xbf)[g] = make_uint2(lo, hi);
            } else {
                uint2 q = ((const uint2*)x)[g];
                v0 = blo(q.x); v1 = bhi(q.x); v2 = blo(q.y); v3 = bhi(q.y);
            }
            int r = __builtin_amdgcn_cvt_pk_fp8_f32(v0, v1, 0, false);
            r = __builtin_amdgcn_cvt_pk_fp8_f32(v2, v3, r, true);
            xf8[g] = (unsigned int)r;
        }
    } else {
        // weights+biases -> bf16: W1l@0 W1r@16384 W2l@32768 W2r@49152 b1@65536 b2@65664
        int idx = (b - NB - 2048) * 256 + t;
        if (idx >= 65792) return;
        const void* src; int off;
        if      (idx < 16384) { src = W1l; off = idx; }
        else if (idx < 32768) { src = W1r; off = idx - 16384; }
        else if (idx < 49152) { src = W2l; off = idx - 32768; }
        else if (idx < 65536) { src = W2r; off = idx - 49152; }
        else if (idx < 65664) { src = b1;  off = idx - 65536; }
        else                  { src = b2;  off = idx - 65664; }
        wbf[idx] = (flags[0] != 0) ? ((const ushort*)src)[off]
                                   : f2b(((const float*)src)[off]);
    }
}

// ---- 2. scan: bucketBase + per-(block,bucket) bases (1 block, NB threads) ----
__global__ __launch_bounds__(NB) void k_bscan(const int* __restrict__ blkcnt,
                                              int* __restrict__ bucketBase,
                                              int* __restrict__ blkbase) {
    __shared__ int s[NB];
    int t = threadIdx.x;
    int tot = 0;
    for (int blk = 0; blk < NB; ++blk) tot += blkcnt[blk * NB + t];
    s[t] = tot; __syncthreads();
    for (int off = 1; off < NB; off <<= 1) {
        int a = (t >= off) ? s[t - off] : 0;
        __syncthreads();
        s[t] += a;
        __syncthreads();
    }
    int excl = s[t] - tot;
    bucketBase[t] = excl;
    if (t == NB - 1) bucketBase[NB] = s[NB - 1];
    int run = excl;
    for (int blk = 0; blk < NB; ++blk) {
        blkbase[blk * NB + t] = run;
        run += blkcnt[blk * NB + t];
    }
}

// ---- 3. bin edges into buckets; packed entry = src | (loc<<20) ----
__global__ __launch_bounds__(256) void k_bin(const void* __restrict__ ei,
                                             const int* __restrict__ blkbase,
                                             int* __restrict__ binned,
                                             const int* __restrict__ flags) {
    __shared__ int bb[NB];
    __shared__ int rank[NB];
    int t = threadIdx.x, blk = blockIdx.x;
    int f = flags[1];
    for (int j = t; j < NB; j += 256) { bb[j] = blkbase[blk * NB + j]; rank[j] = 0; }
    __syncthreads();
    int lo = blk * CHUNK, hi = lo + CHUNK;
    for (int e = lo + t; e < hi; e += 256) {
        int s = idx_at(ei, e, f);
        int d = idx_at(ei, (long)N_EDGES + e, f);
        int b = d / NPB;
        int loc = d - b * NPB;              // 0..390, fits in 9 bits
        int r = atomicAdd(&rank[b], 1);
        binned[bb[b] + r] = s | (loc << 20);
    }
}

// ---- 4. per-bucket CSR in LDS, coalesced flush ----
__global__ __launch_bounds__(256) void k_csr(const int* __restrict__ binned,
                                             const int* __restrict__ bucketBase,
                                             int* __restrict__ rowptr,
                                             int* __restrict__ csr) {
    __shared__ int cnt[400];
    __shared__ int sc[400];
    __shared__ int sh[256];
    __shared__ int stage[STAGE];  // 30 KB
    int t = threadIdx.x, b = blockIdx.x;
    int nodeLo = b * NPB;
    int nC = N_NODES - nodeLo; if (nC > NPB) nC = NPB;
    int eBase = bucketBase[b], eEnd = bucketBase[b + 1];

    for (int j = t; j < 400; j += 256) cnt[j] = 0;
    __syncthreads();
    for (int i = eBase + t; i < eEnd; i += 256)
        atomicAdd(&cnt[binned[i] >> 20], 1);
    __syncthreads();
    int base = t * 2;
    int v0 = (base < 400) ? cnt[base] : 0;
    int v1 = (base + 1 < 400) ? cnt[base + 1] : 0;
    int ssum = v0 + v1;
    sh[t] = ssum; __syncthreads();
    for (int off = 1; off < 256; off <<= 1) {
        int a = (t >= off) ? sh[t - off] : 0;
        __syncthreads();
        sh[t] += a;
        __syncthreads();
    }
    int pre = sh[t] - ssum;
    if (base < 400) sc[base] = pre;
    if (base + 1 < 400) sc[base + 1] = pre + v0;
    __syncthreads();
    for (int j = t; j < nC; j += 256) rowptr[nodeLo + j] = eBase + sc[j];
    if (b == NB - 1) {
        if (t == 0) rowptr[N_NODES] = eEnd;
        if (t < 8) csr[N_EDGES + t] = 0;   // pad for unrolled agg reads
    }
    for (int j = t; j < 400; j += 256) cnt[j] = 0;  // reuse as rank
    __syncthreads();
    for (int i = eBase + t; i < eEnd; i += 256) {
        int p = binned[i];
        int loc = p >> 20;
        int pos = sc[loc] + atomicAdd(&cnt[loc], 1);
        int srcn = p & 0xFFFFF;
        if (pos < STAGE) stage[pos] = srcn;
        else csr[eBase + pos] = srcn;   // statistical never
    }
    __syncthreads();
    int eCnt = eEnd - eBase; if (eCnt > STAGE) eCnt = STAGE;
    for (int j = t; j < eCnt; j += 256) csr[eBase + j] = stage[j];
}

// ---- 5. mean aggregation over fp8 rows: wave per node, 8 loads in flight ----
__global__ __launch_bounds__(256) void k_agg(const ushort* __restrict__ x8,
                                             const int* __restrict__ rowptr,
                                             const int* __restrict__ csr,
                                             ushort* __restrict__ mout) {
    int wid = blockIdx.x * 4 + (threadIdx.x >> 6);
    int lane = threadIdx.x & 63;
    if (wid >= N_NODES) return;
    int beg = __builtin_amdgcn_readfirstlane(rowptr[wid]);
    int end = __builtin_amdgcn_readfirstlane(rowptr[wid + 1]);
    float a0 = 0.f, a1 = 0.f;
    for (int j = beg; j < end; j += 8) {
        ushort p[8];
#pragma unroll
        for (int i = 0; i < 8; ++i) {
            int jj = j + i;
            if (jj > end - 1) jj = end - 1;        // clamp: dup load hits cache
            int idx = __builtin_amdgcn_readfirstlane(csr[jj]);
            p[i] = x8[(long)idx * 64 + lane];      // 2 fp8 feats per lane
        }
#pragma unroll
        for (int i = 0; i < 8; ++i) {
            unsigned int q = (j + i < end) ? (unsigned int)p[i] : 0u;  // fp8 0x00 == 0.0
            f32x2 d = __builtin_amdgcn_cvt_pk_f32_fp8((int)q, false);
            a0 += d.x; a1 += d.y;
        }
    }
    int deg = end - beg;
    float scale = (deg > 0) ? 1.f / (float)deg : 0.f;
    unsigned int packed = ((unsigned int)f2b(a1 * scale) << 16) | (unsigned int)f2b(a0 * scale);
    ((unsigned int*)mout)[wid * 64 + lane] = packed;
}

// ---- 6. fused SAGE linear: out = relu([A0|A1] @ [Wl;Wr]^T + b) ----
// layer1: A1 = bf16 x (select), out -> fp8 h1f8. layer2: A1 = fp8 h1f8, out -> bf16.
__global__ __launch_bounds__(256) void k_gemm(const ushort* __restrict__ A0,
                                              const ushort* __restrict__ A1a,
                                              const ushort* __restrict__ A1b,
                                              const uchar* __restrict__ A1f8,
                                              const ushort* __restrict__ Wl,
                                              const ushort* __restrict__ Wr,
                                              const ushort* __restrict__ bias,
                                              ushort* __restrict__ outb,
                                              uchar* __restrict__ out8,
                                              const int* __restrict__ flags,
                                              int layer1) {
    __shared__ short Ws[4096 * 8];  // 64 KiB fragment-interleaved weights
    int t = threadIdx.x;
    const ushort* A1 = flags[0] ? A1a : A1b;
#pragma unroll
    for (int i = 0; i < 16; ++i) {
        int f = i * 256 + t;
        int lane = f & 63, kk = (f >> 6) & 7, tile = f >> 9;
        int o = tile * 16 + (lane & 15);
        int k0 = kk * 32 + ((lane >> 4) * 8);
        const ushort* wsrc = (k0 < 128) ? (Wl + o * 128 + k0)
                                        : (Wr + o * 128 + (k0 - 128));
        *(short8*)&Ws[f * 8] = *(const short8*)wsrc;
    }
    __syncthreads();

    int wid = t >> 6, lane = t & 63;
    long nbase = (long)blockIdx.x * 64 + (long)wid * 16;
    int arow = (int)nbase + (lane & 15);
    if (arow >= N_NODES) arow = N_NODES - 1;   // clamp (stores guarded)
    int kq = (lane >> 4) * 8;

    short8 afrag[8];
#pragma unroll
    for (int kk = 0; kk < 8; ++kk) {
        int k0 = kk * 32 + kq;
        if (k0 < 128) {
            afrag[kk] = *(const short8*)(A0 + (long)arow * 128 + k0);
        } else if (layer1) {
            afrag[kk] = *(const short8*)(A1 + (long)arow * 128 + (k0 - 128));
        } else {
            const uchar* fp = A1f8 + (long)arow * 128 + (k0 - 128);
            uint2 q = *(const uint2*)fp;
            f32x2 d0 = __builtin_amdgcn_cvt_pk_f32_fp8((int)q.x, false);
            f32x2 d1 = __builtin_amdgcn_cvt_pk_f32_fp8((int)q.x, true);
            f32x2 d2 = __builtin_amdgcn_cvt_pk_f32_fp8((int)q.y, false);
            f32x2 d3 = __builtin_amdgcn_cvt_pk_f32_fp8((int)q.y, true);
            short8 s;
            s[0] = (short)f2b(d0.x); s[1] = (short)f2b(d0.y);
            s[2] = (short)f2b(d1.x); s[3] = (short)f2b(d1.y);
            s[4] = (short)f2b(d2.x); s[5] = (short)f2b(d2.y);
            s[6] = (short)f2b(d3.x); s[7] = (short)f2b(d3.y);
            afrag[kk] = s;
        }
    }

#pragma unroll
    for (int tile = 0; tile < 8; ++tile) {
        f32x4 acc = {0.f, 0.f, 0.f, 0.f};
#pragma unroll
        for (int kk = 0; kk < 8; ++kk) {
            short8 bfrag = *(short8*)&Ws[((tile * 8 + kk) * 64 + lane) * 8];
            acc = __builtin_amdgcn_mfma_f32_16x16x32_bf16(afrag[kk], bfrag, acc, 0, 0, 0);
        }
        int o = tile * 16 + (lane & 15);
        float bo = b2f(bias[o]);
#pragma unroll
        for (int r = 0; r < 4; ++r) {
            long node = nbase + (lane >> 4) * 4 + r;
            if (node < N_NODES) {
                float v = acc[r] + bo;
                v = v > 0.f ? v : 0.f;
                if (layer1) {
                    int pp = __builtin_amdgcn_cvt_pk_fp8_f32(v, v, 0, false);
                    out8[node * 128 + o] = (uchar)pp;
                } else {
                    outb[node * 128 + o] = f2b(v);
                }
            }
        }
    }
}

// ---- 7. fused global mean pool + classifier + log_softmax ----
__global__ __launch_bounds__(256) void k_pool_cls(const ushort* __restrict__ h2,
                                                  const void* __restrict__ batch,
                                                  const void* __restrict__ Wf,
                                                  const void* __restrict__ bfv,
                                                  void* __restrict__ outp,
                                                  const int* __restrict__ flags) {
    int g = blockIdx.x, t = threadIdx.x;
    int wid = t >> 6, lane = t & 63;
    bool f32 = (flags[0] == 0);
    int b64 = flags[2];
    __shared__ int rng[2];
    __shared__ float redA[4][64];
    __shared__ float redB[4][64];
    __shared__ float gv[128];
    __shared__ float lg[10];
    if (t < 2) {
        int v = g + t, lo = 0, hi = N_NODES;
        while (lo < hi) {
            int mid = (lo + hi) >> 1;
            if (idx_at(batch, mid, b64) < v) lo = mid + 1; else hi = mid;
        }
        rng[t] = lo;
    }
    __syncthreads();
    int lo = rng[0], hi = rng[1];
    const unsigned int* xr = (const unsigned int*)h2;
    float a0 = 0.f, a1 = 0.f;
    int n = lo + wid;
    for (; n + 28 < hi; n += 32) {
        unsigned int p[8];
#pragma unroll
        for (int i = 0; i < 8; ++i) p[i] = xr[(long)(n + i * 4) * 64 + lane];
#pragma unroll
        for (int i = 0; i < 8; ++i) { a0 += blo(p[i]); a1 += bhi(p[i]); }
    }
    for (; n < hi; n += 4) {
        unsigned int q = xr[(long)n * 64 + lane];
        a0 += blo(q); a1 += bhi(q);
    }
    redA[wid][lane] = a0;
    redB[wid][lane] = a1;
    __syncthreads();
    if (wid == 0) {
        float s0 = redA[0][lane] + redA[1][lane] + redA[2][lane] + redA[3][lane];
        float s1 = redB[0][lane] + redB[1][lane] + redB[2][lane] + redB[3][lane];
        float c = (hi > lo) ? (float)(hi - lo) : 1.f;
        gv[lane * 2]     = s0 / c;
        gv[lane * 2 + 1] = s1 / c;
    }
    __syncthreads();
    if (t < 10) {
        float s = f32 ? ((const float*)bfv)[t] : b2f(((const ushort*)bfv)[t]);
        for (int k = 0; k < 128; ++k) {
            float wv = f32 ? ((const float*)Wf)[t * 128 + k] : b2f(((const ushort*)Wf)[t * 128 + k]);
            s += gv[k] * wv;
        }
        lg[t] = s;
    }
    __syncthreads();
    if (t == 0) {
        float mx = lg[0];
        for (int i = 1; i < 10; ++i) mx = fmaxf(mx, lg[i]);
        float se = 0.f;
        for (int i = 0; i < 10; ++i) se += expf(lg[i] - mx);
        float lse = mx + logf(se);
        for (int i = 0; i < 10; ++i) {
            float v = lg[i] - lse;
            if (f32) ((float*)outp)[g * 10 + i] = v;
            else     ((ushort*)outp)[g * 10 + i] = f2b(v);
        }
    }
}

extern "C" void kernel_launch(void* const* d_in, const int* in_sizes, int n_in,
                              void* d_out, int out_size, void* d_ws, size_t ws_size,
                              hipStream_t stream) {
    const void* x     = d_in[0];
    const void* ei    = d_in[1];
    const void* batch = d_in[2];
    const void* W1l = d_in[3];
    const void* b1  = d_in[4];
    const void* W1r = d_in[5];
    const void* W2l = d_in[6];
    const void* b2  = d_in[7];
    const void* W2r = d_in[8];
    const void* Wf  = d_in[9];
    const void* bf_ = d_in[10];

    // workspace layout (aliased by lifetime; high-water 83,732,736 B)
    char* w = (char*)d_ws;
    int* flags      = (int*)(w + 0);              // 3 ints
    int* rowptr     = (int*)(w + 640);            // 100001 ints
    ushort* wbf     = (ushort*)(w + 400768);      // 65792 shorts
    int* csr        = (int*)(w + 532480);         // 1600008 ints
    ushort* xbf     = (ushort*)(w + 6932736);     // 12.8M bf16 (x as bf16 when input fp32)
    ushort* mbuf    = (ushort*)(w + 32532736);    // 12.8M bf16 (CSR-era aliases below)
    int* bucketBase = (int*)(w + 32532736);       //   257 ints  (dead after k_csr)
    int* blkcnt     = (int*)(w + 32534016);       //   256*256   (dead after k_bscan)
    int* blkbase    = (int*)(w + 32796160);       //   256*256   (dead after k_bin)
    uchar* h1f8     = (uchar*)(w + 58132736);     // 12.8M fp8 h1
    int* binned     = (int*)(w + 58132736);       //   1.6M int packed (dead before gemm1)
    unsigned int* xf8 = (unsigned int*)(w + 70932736); // 12.8M fp8 x (as uints)
    ushort* h2      = mbuf;                       // gemm2 is wave-row-exclusive

    dim3 blk256(256), blkNB(NB);

    k_detect<<<1, blk256, 0, stream>>>((const unsigned int*)x, (const unsigned int*)ei,
                                       (const int*)batch, flags);
    k_prep<<<NB + 2048 + 257, blk256, 0, stream>>>(ei, x, xbf, xf8,
                                                   W1l, W1r, W2l, W2r, b1, b2,
                                                   wbf, blkcnt, flags);
    k_bscan<<<1, blkNB, 0, stream>>>(blkcnt, bucketBase, blkbase);
    k_bin<<<NB, blk256, 0, stream>>>(ei, blkbase, binned, flags);
    k_csr<<<NB, blk256, 0, stream>>>(binned, bucketBase, rowptr, csr);

    int agrid = (N_NODES + 3) / 4;               // 25000 (wave per node)
    int ggrid = (N_NODES + 63) / 64;             // 1563

    // layer 1: agg over fp8 x -> mbuf(bf16); gemm -> h1f8 (fp8)
    k_agg<<<agrid, blk256, 0, stream>>>((const ushort*)xf8, rowptr, csr, mbuf);
    k_gemm<<<ggrid, blk256, 0, stream>>>(mbuf, (const ushort*)x, xbf, (const uchar*)nullptr,
                                         wbf + 0, wbf + 16384, wbf + 65536,
                                         (ushort*)nullptr, h1f8, flags, 1);
    // layer 2: agg over fp8 h1 -> mbuf; gemm (A1 = fp8 h1) -> h2 (bf16)
    k_agg<<<agrid, blk256, 0, stream>>>((const ushort*)h1f8, rowptr, csr, mbuf);
    k_gemm<<<ggrid, blk256, 0, stream>>>(mbuf, (const ushort*)x, xbf, h1f8,
                                         wbf + 32768, wbf + 49152, wbf + 65664,
                                         h2, (uchar*)nullptr, flags, 0);
    // pool + classify
    k_pool_cls<<<N_GRAPHS, blk256, 0, stream>>>(h2, batch, Wf, bf_, d_out, flags);
}

// Round 7
// 330.508 us; speedup vs baseline: 2.1257x; 1.0811x over previous
//
#include <hip/hip_runtime.h>
#include <hip/hip_bf16.h>

#define N_NODES 100000
#define N_EDGES 1600000
#define N_GRAPHS 512
#define NB 256                 // coarse dst-buckets
#define NPB 391                // nodes per bucket (256*391 = 100096 >= 100000)
#define CHUNK 6250             // edges per binning block (256*6250 = 1.6M exact)
#define STAGE 7680             // LDS csr staging per bucket (mean 6250, sd ~79)

typedef __attribute__((ext_vector_type(8))) short short8;
typedef __attribute__((ext_vector_type(4))) float f32x4;
typedef __attribute__((ext_vector_type(2))) float f32x2;

// ---- bf16 helpers ----
__device__ __forceinline__ float b2f(ushort u) {
    union { unsigned int i; float f; } c; c.i = ((unsigned int)u) << 16; return c.f;
}
__device__ __forceinline__ float blo(unsigned int u) {
    union { unsigned int i; float f; } c; c.i = u << 16; return c.f;
}
__device__ __forceinline__ float bhi(unsigned int u) {
    union { unsigned int i; float f; } c; c.i = u & 0xffff0000u; return c.f;
}
__device__ __forceinline__ ushort f2b(float f) {  // round-to-nearest-even
    union { float f; unsigned int i; } c; c.f = f;
    unsigned int r = (c.i + 0x7fffu + ((c.i >> 16) & 1u)) >> 16;
    return (ushort)r;
}
__device__ __forceinline__ int idx_at(const void* p, long i, int f) {
    return f ? (int)((const long long*)p)[i] : ((const int*)p)[i];
}

// ---- 0. dtype detection ----
// flags[0]: 1 = floats bf16, 0 = fp32 ; flags[1]: edge int64? ; flags[2]: batch int64?
__global__ __launch_bounds__(256) void k_detect(const unsigned int* __restrict__ xw,
                                                const unsigned int* __restrict__ ew,
                                                const int* __restrict__ bw,
                                                int* __restrict__ flags) {
    __shared__ int cf, ce, cb;
    int t = threadIdx.x;
    if (t == 0) { cf = 0; ce = 0; cb = 0; }
    __syncthreads();
    unsigned int w = xw[t];
    unsigned int e = (w >> 7) & 0xffu;
    if (e >= 110u && e <= 130u) atomicAdd(&cf, 1);
    if (t < 128) {
        if (ew[2 * t + 1] != 0u) atomicAdd(&ce, 1);
        if (bw[99001 + 2 * t] != 0) atomicAdd(&cb, 1);
    }
    __syncthreads();
    if (t == 0) {
        flags[0] = (cf >= 128) ? 1 : 0;
        flags[1] = (ce == 0) ? 1 : 0;
        flags[2] = (cb == 0) ? 1 : 0;
    }
}

// ---- 1. fused prep: [0,NB) bucket-hist | [NB,NB+2048) cvt x -> xbf + xf8 | rest cvt_w ----
__global__ __launch_bounds__(256) void k_prep(const void* __restrict__ ei,
                                              const void* __restrict__ x,
                                              ushort* __restrict__ xbf,
                                              unsigned int* __restrict__ xf8,
                                              const void* W1l, const void* W1r,
                                              const void* W2l, const void* W2r,
                                              const void* b1,  const void* b2,
                                              ushort* __restrict__ wbf,
                                              int* __restrict__ blkcnt,
                                              const int* __restrict__ flags) {
    int b = blockIdx.x, t = threadIdx.x;
    if (b < NB) {
        __shared__ int h[NB];
        int f = flags[1];
        for (int j = t; j < NB; j += 256) h[j] = 0;
        __syncthreads();
        int lo = b * CHUNK, hi = lo + CHUNK;
        for (int e = lo + t; e < hi; e += 256) {
            int d = idx_at(ei, (long)N_EDGES + e, f);
            atomicAdd(&h[d / NPB], 1);
        }
        __syncthreads();
        if (t < NB) blkcnt[b * NB + t] = h[t];
    } else if (b < NB + 2048) {
        bool f32src = (flags[0] == 0);
        int vb = b - NB;
        const long nG = (long)N_NODES * 128 / 4;   // 3.2M groups of 4 feats
        for (long g = (long)vb * 256 + t; g < nG; g += 2048L * 256) {
            float v0, v1, v2, v3;
            if (f32src) {
                float4 vv = ((const float4*)x)[g];
                v0 = vv.x; v1 = vv.y; v2 = vv.z; v3 = vv.w;
                unsigned int lo = (unsigned int)f2b(v0) | ((unsigned int)f2b(v1) << 16);
                unsigned int hi = (unsigned int)f2b(v2) | ((unsigned int)f2b(v3) << 16);
                ((uint2*)xbf)[g] = make_uint2(lo, hi);
            } else {
                uint2 q = ((const uint2*)x)[g];
                v0 = blo(q.x); v1 = bhi(q.x); v2 = blo(q.y); v3 = bhi(q.y);
            }
            int r = __builtin_amdgcn_cvt_pk_fp8_f32(v0, v1, 0, false);
            r = __builtin_amdgcn_cvt_pk_fp8_f32(v2, v3, r, true);
            xf8[g] = (unsigned int)r;
        }
    } else {
        // weights+biases -> bf16: W1l@0 W1r@16384 W2l@32768 W2r@49152 b1@65536 b2@65664
        int idx = (b - NB - 2048) * 256 + t;
        if (idx >= 65792) return;
        const void* src; int off;
        if      (idx < 16384) { src = W1l; off = idx; }
        else if (idx < 32768) { src = W1r; off = idx - 16384; }
        else if (idx < 49152) { src = W2l; off = idx - 32768; }
        else if (idx < 65536) { src = W2r; off = idx - 49152; }
        else if (idx < 65664) { src = b1;  off = idx - 65536; }
        else                  { src = b2;  off = idx - 65664; }
        wbf[idx] = (flags[0] != 0) ? ((const ushort*)src)[off]
                                   : f2b(((const float*)src)[off]);
    }
}

// ---- 2. scan: bucketBase + per-(block,bucket) bases (1 block, NB threads) ----
__global__ __launch_bounds__(NB) void k_bscan(const int* __restrict__ blkcnt,
                                              int* __restrict__ bucketBase,
                                              int* __restrict__ blkbase) {
    __shared__ int s[NB];
    int t = threadIdx.x;
    int tot = 0;
    for (int blk = 0; blk < NB; ++blk) tot += blkcnt[blk * NB + t];
    s[t] = tot; __syncthreads();
    for (int off = 1; off < NB; off <<= 1) {
        int a = (t >= off) ? s[t - off] : 0;
        __syncthreads();
        s[t] += a;
        __syncthreads();
    }
    int excl = s[t] - tot;
    bucketBase[t] = excl;
    if (t == NB - 1) bucketBase[NB] = s[NB - 1];
    int run = excl;
    for (int blk = 0; blk < NB; ++blk) {
        blkbase[blk * NB + t] = run;
        run += blkcnt[blk * NB + t];
    }
}

// ---- 3. bin edges into buckets; packed entry = src | (loc<<20) ----
__global__ __launch_bounds__(256) void k_bin(const void* __restrict__ ei,
                                             const int* __restrict__ blkbase,
                                             int* __restrict__ binned,
                                             const int* __restrict__ flags) {
    __shared__ int bb[NB];
    __shared__ int rank[NB];
    int t = threadIdx.x, blk = blockIdx.x;
    int f = flags[1];
    for (int j = t; j < NB; j += 256) { bb[j] = blkbase[blk * NB + j]; rank[j] = 0; }
    __syncthreads();
    int lo = blk * CHUNK, hi = lo + CHUNK;
    for (int e = lo + t; e < hi; e += 256) {
        int s = idx_at(ei, e, f);
        int d = idx_at(ei, (long)N_EDGES + e, f);
        int b = d / NPB;
        int loc = d - b * NPB;              // 0..390, fits in 9 bits
        int r = atomicAdd(&rank[b], 1);
        binned[bb[b] + r] = s | (loc << 20);
    }
}

// ---- 4. per-bucket CSR in LDS, coalesced flush ----
__global__ __launch_bounds__(256) void k_csr(const int* __restrict__ binned,
                                             const int* __restrict__ bucketBase,
                                             int* __restrict__ rowptr,
                                             int* __restrict__ csr) {
    __shared__ int cnt[400];
    __shared__ int sc[400];
    __shared__ int sh[256];
    __shared__ int stage[STAGE];  // 30 KB
    int t = threadIdx.x, b = blockIdx.x;
    int nodeLo = b * NPB;
    int nC = N_NODES - nodeLo; if (nC > NPB) nC = NPB;
    int eBase = bucketBase[b], eEnd = bucketBase[b + 1];

    for (int j = t; j < 400; j += 256) cnt[j] = 0;
    __syncthreads();
    for (int i = eBase + t; i < eEnd; i += 256)
        atomicAdd(&cnt[binned[i] >> 20], 1);
    __syncthreads();
    int base = t * 2;
    int v0 = (base < 400) ? cnt[base] : 0;
    int v1 = (base + 1 < 400) ? cnt[base + 1] : 0;
    int ssum = v0 + v1;
    sh[t] = ssum; __syncthreads();
    for (int off = 1; off < 256; off <<= 1) {
        int a = (t >= off) ? sh[t - off] : 0;
        __syncthreads();
        sh[t] += a;
        __syncthreads();
    }
    int pre = sh[t] - ssum;
    if (base < 400) sc[base] = pre;
    if (base + 1 < 400) sc[base + 1] = pre + v0;
    __syncthreads();
    for (int j = t; j < nC; j += 256) rowptr[nodeLo + j] = eBase + sc[j];
    if (b == NB - 1) {
        if (t == 0) rowptr[N_NODES] = eEnd;
        if (t < 64) csr[N_EDGES + t] = 0;   // pad for vectorized agg index loads
    }
    for (int j = t; j < 400; j += 256) cnt[j] = 0;  // reuse as rank
    __syncthreads();
    for (int i = eBase + t; i < eEnd; i += 256) {
        int p = binned[i];
        int loc = p >> 20;
        int pos = sc[loc] + atomicAdd(&cnt[loc], 1);
        int srcn = p & 0xFFFFF;
        if (pos < STAGE) stage[pos] = srcn;
        else csr[eBase + pos] = srcn;   // statistical never
    }
    __syncthreads();
    int eCnt = eEnd - eBase; if (eCnt > STAGE) eCnt = STAGE;
    for (int j = t; j < eCnt; j += 256) csr[eBase + j] = stage[j];
}

// ---- 5. mean aggregation over fp8 rows: 2 nodes per wave (32 lanes each),
//      register-resident csr indices (vector load + ds_bpermute), 16 rows in flight ----
__global__ __launch_bounds__(256) void k_agg(const unsigned int* __restrict__ x32,
                                             const int* __restrict__ rowptr,
                                             const int* __restrict__ csr,
                                             uint2* __restrict__ mout) {
    int wv = blockIdx.x * 4 + (threadIdx.x >> 6);   // wave id, 2 nodes per wave
    int lane = threadIdx.x & 63;
    int li = lane & 31;                             // lane within half
    int node = wv * 2 + (lane >> 5);                // nodes 2wv (lanes 0-31), 2wv+1 (32-63)
    if (node >= N_NODES) return;                    // N even: whole wave uniform
    int beg = rowptr[node];
    int end = rowptr[node + 1];
    int deg = end - beg;
    int degO = __shfl_xor(deg, 32);
    int degmax = __builtin_amdgcn_readfirstlane(deg > degO ? deg : degO);
    float a0 = 0.f, a1 = 0.f, a2 = 0.f, a3 = 0.f;
    for (int j = 0; j < degmax; j += 32) {
        // up to 32 indices per half, register-resident (csr padded past N_EDGES)
        int pos = beg + j + li;
        if (pos > end - 1) pos = (deg > 0) ? end - 1 : 0;
        int vidx = csr[pos];
#pragma unroll
        for (int c = 0; c < 32; c += 8) {
            if (j + c >= degmax) break;             // wave-uniform
            unsigned int p[8];
#pragma unroll
            for (int i = 0; i < 8; ++i) {
                int idx = __shfl(vidx, (c + i) | (lane & 32));
                p[i] = x32[(long)idx * 32 + li];    // 4 fp8 feats per lane
            }
#pragma unroll
            for (int i = 0; i < 8; ++i) {
                unsigned int q = (j + c + i < deg) ? p[i] : 0u;  // fp8 0x00 == 0.0
                f32x2 d0 = __builtin_amdgcn_cvt_pk_f32_fp8((int)q, false);
                f32x2 d1 = __builtin_amdgcn_cvt_pk_f32_fp8((int)q, true);
                a0 += d0.x; a1 += d0.y; a2 += d1.x; a3 += d1.y;
            }
        }
    }
    float scale = (deg > 0) ? 1.f / (float)deg : 0.f;
    unsigned int lo = (unsigned int)f2b(a0 * scale) | ((unsigned int)f2b(a1 * scale) << 16);
    unsigned int hi = (unsigned int)f2b(a2 * scale) | ((unsigned int)f2b(a3 * scale) << 16);
    mout[(long)node * 32 + li] = make_uint2(lo, hi);
}

// ---- 6. fused SAGE linear: out = relu([A0|A1] @ [Wl;Wr]^T + b) ----
// layer1: A1 = bf16 x (select), out -> fp8 h1f8. layer2: A1 = fp8 h1f8, out -> bf16.
__global__ __launch_bounds__(256) void k_gemm(const ushort* __restrict__ A0,
                                              const ushort* __restrict__ A1a,
                                              const ushort* __restrict__ A1b,
                                              const uchar* __restrict__ A1f8,
                                              const ushort* __restrict__ Wl,
                                              const ushort* __restrict__ Wr,
                                              const ushort* __restrict__ bias,
                                              ushort* __restrict__ outb,
                                              uchar* __restrict__ out8,
                                              const int* __restrict__ flags,
                                              int layer1) {
    __shared__ short Ws[4096 * 8];  // 64 KiB fragment-interleaved weights
    int t = threadIdx.x;
    const ushort* A1 = flags[0] ? A1a : A1b;
#pragma unroll
    for (int i = 0; i < 16; ++i) {
        int f = i * 256 + t;
        int lane = f & 63, kk = (f >> 6) & 7, tile = f >> 9;
        int o = tile * 16 + (lane & 15);
        int k0 = kk * 32 + ((lane >> 4) * 8);
        const ushort* wsrc = (k0 < 128) ? (Wl + o * 128 + k0)
                                        : (Wr + o * 128 + (k0 - 128));
        *(short8*)&Ws[f * 8] = *(const short8*)wsrc;
    }
    __syncthreads();

    int wid = t >> 6, lane = t & 63;
    long nbase = (long)blockIdx.x * 64 + (long)wid * 16;
    int arow = (int)nbase + (lane & 15);
    if (arow >= N_NODES) arow = N_NODES - 1;   // clamp (stores guarded)
    int kq = (lane >> 4) * 8;

    short8 afrag[8];
#pragma unroll
    for (int kk = 0; kk < 8; ++kk) {
        int k0 = kk * 32 + kq;
        if (k0 < 128) {
            afrag[kk] = *(const short8*)(A0 + (long)arow * 128 + k0);
        } else if (layer1) {
            afrag[kk] = *(const short8*)(A1 + (long)arow * 128 + (k0 - 128));
        } else {
            const uchar* fp = A1f8 + (long)arow * 128 + (k0 - 128);
            uint2 q = *(const uint2*)fp;
            f32x2 d0 = __builtin_amdgcn_cvt_pk_f32_fp8((int)q.x, false);
            f32x2 d1 = __builtin_amdgcn_cvt_pk_f32_fp8((int)q.x, true);
            f32x2 d2 = __builtin_amdgcn_cvt_pk_f32_fp8((int)q.y, false);
            f32x2 d3 = __builtin_amdgcn_cvt_pk_f32_fp8((int)q.y, true);
            short8 s;
            s[0] = (short)f2b(d0.x); s[1] = (short)f2b(d0.y);
            s[2] = (short)f2b(d1.x); s[3] = (short)f2b(d1.y);
            s[4] = (short)f2b(d2.x); s[5] = (short)f2b(d2.y);
            s[6] = (short)f2b(d3.x); s[7] = (short)f2b(d3.y);
            afrag[kk] = s;
        }
    }

#pragma unroll
    for (int tile = 0; tile < 8; ++tile) {
        f32x4 acc = {0.f, 0.f, 0.f, 0.f};
#pragma unroll
        for (int kk = 0; kk < 8; ++kk) {
            short8 bfrag = *(short8*)&Ws[((tile * 8 + kk) * 64 + lane) * 8];
            acc = __builtin_amdgcn_mfma_f32_16x16x32_bf16(afrag[kk], bfrag, acc, 0, 0, 0);
        }
        int o = tile * 16 + (lane & 15);
        float bo = b2f(bias[o]);
#pragma unroll
        for (int r = 0; r < 4; ++r) {
            long node = nbase + (lane >> 4) * 4 + r;
            if (node < N_NODES) {
                float v = acc[r] + bo;
                v = v > 0.f ? v : 0.f;
                if (layer1) {
                    int pp = __builtin_amdgcn_cvt_pk_fp8_f32(v, v, 0, false);
                    out8[node * 128 + o] = (uchar)pp;
                } else {
                    outb[node * 128 + o] = f2b(v);
                }
            }
        }
    }
}

// ---- 7. fused global mean pool + classifier + log_softmax ----
__global__ __launch_bounds__(256) void k_pool_cls(const ushort* __restrict__ h2,
                                                  const void* __restrict__ batch,
                                                  const void* __restrict__ Wf,
                                                  const void* __restrict__ bfv,
                                                  void* __restrict__ outp,
                                                  const int* __restrict__ flags) {
    int g = blockIdx.x, t = threadIdx.x;
    int wid = t >> 6, lane = t & 63;
    bool f32 = (flags[0] == 0);
    int b64 = flags[2];
    __shared__ int rng[2];
    __shared__ float redA[4][64];
    __shared__ float redB[4][64];
    __shared__ float gv[128];
    __shared__ float lg[10];
    if (t < 2) {
        int v = g + t, lo = 0, hi = N_NODES;
        while (lo < hi) {
            int mid = (lo + hi) >> 1;
            if (idx_at(batch, mid, b64) < v) lo = mid + 1; else hi = mid;
        }
        rng[t] = lo;
    }
    __syncthreads();
    int lo = rng[0], hi = rng[1];
    const unsigned int* xr = (const unsigned int*)h2;
    float a0 = 0.f, a1 = 0.f;
    int n = lo + wid;
    for (; n + 28 < hi; n += 32) {
        unsigned int p[8];
#pragma unroll
        for (int i = 0; i < 8; ++i) p[i] = xr[(long)(n + i * 4) * 64 + lane];
#pragma unroll
        for (int i = 0; i < 8; ++i) { a0 += blo(p[i]); a1 += bhi(p[i]); }
    }
    for (; n < hi; n += 4) {
        unsigned int q = xr[(long)n * 64 + lane];
        a0 += blo(q); a1 += bhi(q);
    }
    redA[wid][lane] = a0;
    redB[wid][lane] = a1;
    __syncthreads();
    if (wid == 0) {
        float s0 = redA[0][lane] + redA[1][lane] + redA[2][lane] + redA[3][lane];
        float s1 = redB[0][lane] + redB[1][lane] + redB[2][lane] + redB[3][lane];
        float c = (hi > lo) ? (float)(hi - lo) : 1.f;
        gv[lane * 2]     = s0 / c;
        gv[lane * 2 + 1] = s1 / c;
    }
    __syncthreads();
    if (t < 10) {
        float s = f32 ? ((const float*)bfv)[t] : b2f(((const ushort*)bfv)[t]);
        for (int k = 0; k < 128; ++k) {
            float wv = f32 ? ((const float*)Wf)[t * 128 + k] : b2f(((const ushort*)Wf)[t * 128 + k]);
            s += gv[k] * wv;
        }
        lg[t] = s;
    }
    __syncthreads();
    if (t == 0) {
        float mx = lg[0];
        for (int i = 1; i < 10; ++i) mx = fmaxf(mx, lg[i]);
        float se = 0.f;
        for (int i = 0; i < 10; ++i) se += expf(lg[i] - mx);
        float lse = mx + logf(se);
        for (int i = 0; i < 10; ++i) {
            float v = lg[i] - lse;
            if (f32) ((float*)outp)[g * 10 + i] = v;
            else     ((ushort*)outp)[g * 10 + i] = f2b(v);
        }
    }
}

extern "C" void kernel_launch(void* const* d_in, const int* in_sizes, int n_in,
                              void* d_out, int out_size, void* d_ws, size_t ws_size,
                              hipStream_t stream) {
    const void* x     = d_in[0];
    const void* ei    = d_in[1];
    const void* batch = d_in[2];
    const void* W1l = d_in[3];
    const void* b1  = d_in[4];
    const void* W1r = d_in[5];
    const void* W2l = d_in[6];
    const void* b2  = d_in[7];
    const void* W2r = d_in[8];
    const void* Wf  = d_in[9];
    const void* bf_ = d_in[10];

    // workspace layout (aliased by lifetime; high-water 83,732,736 B)
    char* w = (char*)d_ws;
    int* flags      = (int*)(w + 0);              // 3 ints
    int* rowptr     = (int*)(w + 640);            // 100001 ints
    ushort* wbf     = (ushort*)(w + 400768);      // 65792 shorts
    int* csr        = (int*)(w + 532480);         // 1600064 ints (64 pad)
    ushort* xbf     = (ushort*)(w + 6933248);     // 12.8M bf16 (x as bf16 when input fp32)
    ushort* mbuf    = (ushort*)(w + 32533248);    // 12.8M bf16 (CSR-era aliases below)
    int* bucketBase = (int*)(w + 32533248);       //   257 ints  (dead after k_csr)
    int* blkcnt     = (int*)(w + 32534528);       //   256*256   (dead after k_bscan)
    int* blkbase    = (int*)(w + 32796672);       //   256*256   (dead after k_bin)
    uchar* h1f8     = (uchar*)(w + 58133248);     // 12.8M fp8 h1
    int* binned     = (int*)(w + 58133248);       //   1.6M int packed (dead before gemm1)
    unsigned int* xf8 = (unsigned int*)(w + 70933248); // 12.8M fp8 x (as uints)
    ushort* h2      = mbuf;                       // gemm2 is wave-row-exclusive

    dim3 blk256(256), blkNB(NB);

    k_detect<<<1, blk256, 0, stream>>>((const unsigned int*)x, (const unsigned int*)ei,
                                       (const int*)batch, flags);
    k_prep<<<NB + 2048 + 257, blk256, 0, stream>>>(ei, x, xbf, xf8,
                                                   W1l, W1r, W2l, W2r, b1, b2,
                                                   wbf, blkcnt, flags);
    k_bscan<<<1, blkNB, 0, stream>>>(blkcnt, bucketBase, blkbase);
    k_bin<<<NB, blk256, 0, stream>>>(ei, blkbase, binned, flags);
    k_csr<<<NB, blk256, 0, stream>>>(binned, bucketBase, rowptr, csr);

    int agrid = (N_NODES / 2 + 3) / 4;           // 12500 (2 nodes per wave, 4 waves/block)
    int ggrid = (N_NODES + 63) / 64;             // 1563

    // layer 1: agg over fp8 x -> mbuf(bf16); gemm -> h1f8 (fp8)
    k_agg<<<agrid, blk256, 0, stream>>>(xf8, rowptr, csr, (uint2*)mbuf);
    k_gemm<<<ggrid, blk256, 0, stream>>>(mbuf, (const ushort*)x, xbf, (const uchar*)nullptr,
                                         wbf + 0, wbf + 16384, wbf + 65536,
                                         (ushort*)nullptr, h1f8, flags, 1);
    // layer 2: agg over fp8 h1 -> mbuf; gemm (A1 = fp8 h1) -> h2 (bf16)
    k_agg<<<agrid, blk256, 0, stream>>>((const unsigned int*)h1f8, rowptr, csr, (uint2*)mbuf);
    k_gemm<<<ggrid, blk256, 0, stream>>>(mbuf, (const ushort*)x, xbf, h1f8,
                                         wbf + 32768, wbf + 49152, wbf + 65664,
                                         h2, (uchar*)nullptr, flags, 0);
    // pool + classify
    k_pool_cls<<<N_GRAPHS, blk256, 0, stream>>>(h2, batch, Wf, bf_, d_out, flags);
}

// Round 8
// 319.446 us; speedup vs baseline: 2.1993x; 1.0346x over previous
//
#include <hip/hip_runtime.h>
#include <hip/hip_bf16.h>

#define N_NODES 100000
#define N_EDGES 1600000
#define N_GRAPHS 512
#define NB 256                 // coarse dst-buckets
#define NPB 391                // nodes per bucket (256*391 = 100096 >= 100000)
#define CHUNK 6250             // edges per binning block (256*6250 = 1.6M exact)
#define STAGE 7680             // LDS csr staging per bucket (mean 6250, sd ~79)

typedef __attribute__((ext_vector_type(8))) short short8;
typedef __attribute__((ext_vector_type(4))) float f32x4;
typedef __attribute__((ext_vector_type(2))) float f32x2;

// ---- bf16 helpers ----
__device__ __forceinline__ float b2f(ushort u) {
    union { unsigned int i; float f; } c; c.i = ((unsigned int)u) << 16; return c.f;
}
__device__ __forceinline__ float blo(unsigned int u) {
    union { unsigned int i; float f; } c; c.i = u << 16; return c.f;
}
__device__ __forceinline__ float bhi(unsigned int u) {
    union { unsigned int i; float f; } c; c.i = u & 0xffff0000u; return c.f;
}
__device__ __forceinline__ ushort f2b(float f) {  // round-to-nearest-even
    union { float f; unsigned int i; } c; c.f = f;
    unsigned int r = (c.i + 0x7fffu + ((c.i >> 16) & 1u)) >> 16;
    return (ushort)r;
}
__device__ __forceinline__ int idx_at(const void* p, long i, int f) {
    return f ? (int)((const long long*)p)[i] : ((const int*)p)[i];
}
// decode 8 packed fp8 (uint2) -> short8 of bf16
__device__ __forceinline__ short8 dec8(const uchar* p) {
    uint2 q = *(const uint2*)p;
    f32x2 d0 = __builtin_amdgcn_cvt_pk_f32_fp8((int)q.x, false);
    f32x2 d1 = __builtin_amdgcn_cvt_pk_f32_fp8((int)q.x, true);
    f32x2 d2 = __builtin_amdgcn_cvt_pk_f32_fp8((int)q.y, false);
    f32x2 d3 = __builtin_amdgcn_cvt_pk_f32_fp8((int)q.y, true);
    short8 s;
    s[0] = (short)f2b(d0.x); s[1] = (short)f2b(d0.y);
    s[2] = (short)f2b(d1.x); s[3] = (short)f2b(d1.y);
    s[4] = (short)f2b(d2.x); s[5] = (short)f2b(d2.y);
    s[6] = (short)f2b(d3.x); s[7] = (short)f2b(d3.y);
    return s;
}

// ---- 0. dtype detection ----
// flags[0]: 1 = floats bf16, 0 = fp32 ; flags[1]: edge int64? ; flags[2]: batch int64?
__global__ __launch_bounds__(256) void k_detect(const unsigned int* __restrict__ xw,
                                                const unsigned int* __restrict__ ew,
                                                const int* __restrict__ bw,
                                                int* __restrict__ flags) {
    __shared__ int cf, ce, cb;
    int t = threadIdx.x;
    if (t == 0) { cf = 0; ce = 0; cb = 0; }
    __syncthreads();
    unsigned int w = xw[t];
    unsigned int e = (w >> 7) & 0xffu;
    if (e >= 110u && e <= 130u) atomicAdd(&cf, 1);
    if (t < 128) {
        if (ew[2 * t + 1] != 0u) atomicAdd(&ce, 1);
        if (bw[99001 + 2 * t] != 0) atomicAdd(&cb, 1);
    }
    __syncthreads();
    if (t == 0) {
        flags[0] = (cf >= 128) ? 1 : 0;
        flags[1] = (ce == 0) ? 1 : 0;
        flags[2] = (cb == 0) ? 1 : 0;
    }
}

// ---- 1. fused prep: [0,NB) bucket-hist | [NB,NB+2048) cvt x -> xbf + xf8 | rest cvt_w ----
__global__ __launch_bounds__(256) void k_prep(const void* __restrict__ ei,
                                              const void* __restrict__ x,
                                              ushort* __restrict__ xbf,
                                              unsigned int* __restrict__ xf8,
                                              const void* W1l, const void* W1r,
                                              const void* W2l, const void* W2r,
                                              const void* b1,  const void* b2,
                                              ushort* __restrict__ wbf,
                                              int* __restrict__ blkcnt,
                                              const int* __restrict__ flags) {
    int b = blockIdx.x, t = threadIdx.x;
    if (b < NB) {
        __shared__ int h[NB];
        int f = flags[1];
        for (int j = t; j < NB; j += 256) h[j] = 0;
        __syncthreads();
        int lo = b * CHUNK, hi = lo + CHUNK;
        for (int e = lo + t; e < hi; e += 256) {
            int d = idx_at(ei, (long)N_EDGES + e, f);
            atomicAdd(&h[d / NPB], 1);
        }
        __syncthreads();
        if (t < NB) blkcnt[b * NB + t] = h[t];
    } else if (b < NB + 2048) {
        bool f32src = (flags[0] == 0);
        int vb = b - NB;
        const long nG = (long)N_NODES * 128 / 4;   // 3.2M groups of 4 feats
        for (long g = (long)vb * 256 + t; g < nG; g += 2048L * 256) {
            float v0, v1, v2, v3;
            if (f32src) {
                float4 vv = ((const float4*)x)[g];
                v0 = vv.x; v1 = vv.y; v2 = vv.z; v3 = vv.w;
                unsigned int lo = (unsigned int)f2b(v0) | ((unsigned int)f2b(v1) << 16);
                unsigned int hi = (unsigned int)f2b(v2) | ((unsigned int)f2b(v3) << 16);
                ((uint2*)xbf)[g] = make_uint2(lo, hi);
            } else {
                uint2 q = ((const uint2*)x)[g];
                v0 = blo(q.x); v1 = bhi(q.x); v2 = blo(q.y); v3 = bhi(q.y);
            }
            int r = __builtin_amdgcn_cvt_pk_fp8_f32(v0, v1, 0, false);
            r = __builtin_amdgcn_cvt_pk_fp8_f32(v2, v3, r, true);
            xf8[g] = (unsigned int)r;
        }
    } else {
        // weights+biases -> bf16: W1l@0 W1r@16384 W2l@32768 W2r@49152 b1@65536 b2@65664
        int idx = (b - NB - 2048) * 256 + t;
        if (idx >= 65792) return;
        const void* src; int off;
        if      (idx < 16384) { src = W1l; off = idx; }
        else if (idx < 32768) { src = W1r; off = idx - 16384; }
        else if (idx < 49152) { src = W2l; off = idx - 32768; }
        else if (idx < 65536) { src = W2r; off = idx - 49152; }
        else if (idx < 65664) { src = b1;  off = idx - 65536; }
        else                  { src = b2;  off = idx - 65664; }
        wbf[idx] = (flags[0] != 0) ? ((const ushort*)src)[off]
                                   : f2b(((const float*)src)[off]);
    }
}

// ---- 2. scan: bucketBase + per-(block,bucket) bases (1 block, NB threads) ----
__global__ __launch_bounds__(NB) void k_bscan(const int* __restrict__ blkcnt,
                                              int* __restrict__ bucketBase,
                                              int* __restrict__ blkbase) {
    __shared__ int s[NB];
    int t = threadIdx.x;
    int tot = 0;
    for (int blk = 0; blk < NB; ++blk) tot += blkcnt[blk * NB + t];
    s[t] = tot; __syncthreads();
    for (int off = 1; off < NB; off <<= 1) {
        int a = (t >= off) ? s[t - off] : 0;
        __syncthreads();
        s[t] += a;
        __syncthreads();
    }
    int excl = s[t] - tot;
    bucketBase[t] = excl;
    if (t == NB - 1) bucketBase[NB] = s[NB - 1];
    int run = excl;
    for (int blk = 0; blk < NB; ++blk) {
        blkbase[blk * NB + t] = run;
        run += blkcnt[blk * NB + t];
    }
}

// ---- 3. bin edges into buckets; packed entry = src | (loc<<20) ----
__global__ __launch_bounds__(256) void k_bin(const void* __restrict__ ei,
                                             const int* __restrict__ blkbase,
                                             int* __restrict__ binned,
                                             const int* __restrict__ flags) {
    __shared__ int bb[NB];
    __shared__ int rank[NB];
    int t = threadIdx.x, blk = blockIdx.x;
    int f = flags[1];
    for (int j = t; j < NB; j += 256) { bb[j] = blkbase[blk * NB + j]; rank[j] = 0; }
    __syncthreads();
    int lo = blk * CHUNK, hi = lo + CHUNK;
    for (int e = lo + t; e < hi; e += 256) {
        int s = idx_at(ei, e, f);
        int d = idx_at(ei, (long)N_EDGES + e, f);
        int b = d / NPB;
        int loc = d - b * NPB;              // 0..390, fits in 9 bits
        int r = atomicAdd(&rank[b], 1);
        binned[bb[b] + r] = s | (loc << 20);
    }
}

// ---- 4. per-bucket CSR in LDS, coalesced flush ----
__global__ __launch_bounds__(256) void k_csr(const int* __restrict__ binned,
                                             const int* __restrict__ bucketBase,
                                             int* __restrict__ rowptr,
                                             int* __restrict__ csr) {
    __shared__ int cnt[400];
    __shared__ int sc[400];
    __shared__ int sh[256];
    __shared__ int stage[STAGE];  // 30 KB
    int t = threadIdx.x, b = blockIdx.x;
    int nodeLo = b * NPB;
    int nC = N_NODES - nodeLo; if (nC > NPB) nC = NPB;
    int eBase = bucketBase[b], eEnd = bucketBase[b + 1];

    for (int j = t; j < 400; j += 256) cnt[j] = 0;
    __syncthreads();
    for (int i = eBase + t; i < eEnd; i += 256)
        atomicAdd(&cnt[binned[i] >> 20], 1);
    __syncthreads();
    int base = t * 2;
    int v0 = (base < 400) ? cnt[base] : 0;
    int v1 = (base + 1 < 400) ? cnt[base + 1] : 0;
    int ssum = v0 + v1;
    sh[t] = ssum; __syncthreads();
    for (int off = 1; off < 256; off <<= 1) {
        int a = (t >= off) ? sh[t - off] : 0;
        __syncthreads();
        sh[t] += a;
        __syncthreads();
    }
    int pre = sh[t] - ssum;
    if (base < 400) sc[base] = pre;
    if (base + 1 < 400) sc[base + 1] = pre + v0;
    __syncthreads();
    for (int j = t; j < nC; j += 256) rowptr[nodeLo + j] = eBase + sc[j];
    if (b == NB - 1) {
        if (t == 0) rowptr[N_NODES] = eEnd;
        if (t < 64) csr[N_EDGES + t] = 0;   // pad (vector index loads are clamped anyway)
    }
    for (int j = t; j < 400; j += 256) cnt[j] = 0;  // reuse as rank
    __syncthreads();
    for (int i = eBase + t; i < eEnd; i += 256) {
        int p = binned[i];
        int loc = p >> 20;
        int pos = sc[loc] + atomicAdd(&cnt[loc], 1);
        int srcn = p & 0xFFFFF;
        if (pos < STAGE) stage[pos] = srcn;
        else csr[eBase + pos] = srcn;   // statistical never
    }
    __syncthreads();
    int eCnt = eEnd - eBase; if (eCnt > STAGE) eCnt = STAGE;
    for (int j = t; j < eCnt; j += 256) csr[eBase + j] = stage[j];
}

// ---- 5. mean aggregation over fp8 rows: 4 nodes per wave (16 lanes each),
//      uint2 gathers (8 fp8 feats/lane), register csr indices via shfl, fp8 mean out ----
__global__ __launch_bounds__(256) void k_agg(const uint2* __restrict__ x16,
                                             const int* __restrict__ rowptr,
                                             const int* __restrict__ csr,
                                             uint2* __restrict__ mout) {
    int wv = blockIdx.x * 4 + (threadIdx.x >> 6);   // wave id; 4 nodes per wave
    int lane = threadIdx.x & 63;
    int li = lane & 15;                             // lane within node-quarter
    int node = wv * 4 + (lane >> 4);                // 100000 % 4 == 0: no tail
    int beg = rowptr[node];
    int end = rowptr[node + 1];
    int deg = end - beg;
    int m = deg;
    m = max(m, __shfl_xor(m, 16));
    m = max(m, __shfl_xor(m, 32));
    int degmax = __builtin_amdgcn_readfirstlane(m);
    float a0 = 0.f, a1 = 0.f, a2 = 0.f, a3 = 0.f;
    float a4 = 0.f, a5 = 0.f, a6 = 0.f, a7 = 0.f;
    for (int j = 0; j < degmax; j += 16) {
        // up to 16 indices per quarter, register-resident
        int pos = beg + j + li;
        if (pos > end - 1) pos = (deg > 0) ? end - 1 : 0;
        int vidx = csr[pos];
#pragma unroll
        for (int c = 0; c < 16; c += 8) {
            if (j + c >= degmax) break;             // wave-uniform
            uint2 p[8];
#pragma unroll
            for (int i = 0; i < 8; ++i) {
                int idx = __shfl(vidx, (c + i) | (lane & 48));
                p[i] = x16[(long)idx * 16 + li];    // 8 fp8 feats per lane
            }
#pragma unroll
            for (int i = 0; i < 8; ++i) {
                bool ok = (j + c + i < deg);
                unsigned int qx = ok ? p[i].x : 0u;  // fp8 0x00 == 0.0
                unsigned int qy = ok ? p[i].y : 0u;
                f32x2 d0 = __builtin_amdgcn_cvt_pk_f32_fp8((int)qx, false);
                f32x2 d1 = __builtin_amdgcn_cvt_pk_f32_fp8((int)qx, true);
                f32x2 d2 = __builtin_amdgcn_cvt_pk_f32_fp8((int)qy, false);
                f32x2 d3 = __builtin_amdgcn_cvt_pk_f32_fp8((int)qy, true);
                a0 += d0.x; a1 += d0.y; a2 += d1.x; a3 += d1.y;
                a4 += d2.x; a5 += d2.y; a6 += d3.x; a7 += d3.y;
            }
        }
    }
    float s = (deg > 0) ? 1.f / (float)deg : 0.f;
    int r0 = __builtin_amdgcn_cvt_pk_fp8_f32(a0 * s, a1 * s, 0, false);
    r0 = __builtin_amdgcn_cvt_pk_fp8_f32(a2 * s, a3 * s, r0, true);
    int r1 = __builtin_amdgcn_cvt_pk_fp8_f32(a4 * s, a5 * s, 0, false);
    r1 = __builtin_amdgcn_cvt_pk_fp8_f32(a6 * s, a7 * s, r1, true);
    mout[(long)node * 16 + li] = make_uint2((unsigned int)r0, (unsigned int)r1);
}

// ---- 6. fused SAGE linear: out = relu([A0|A1] @ [Wl;Wr]^T + b) ----
// A0 = fp8 mean (both layers). layer1: A1 = bf16 x (select), out -> fp8 h1f8.
// layer2: A1 = fp8 h1f8, out -> bf16 h2.
__global__ __launch_bounds__(256) void k_gemm(const uchar* __restrict__ A0f8,
                                              const ushort* __restrict__ A1a,
                                              const ushort* __restrict__ A1b,
                                              const uchar* __restrict__ A1f8,
                                              const ushort* __restrict__ Wl,
                                              const ushort* __restrict__ Wr,
                                              const ushort* __restrict__ bias,
                                              ushort* __restrict__ outb,
                                              uchar* __restrict__ out8,
                                              const int* __restrict__ flags,
                                              int layer1) {
    __shared__ short Ws[4096 * 8];  // 64 KiB fragment-interleaved weights
    int t = threadIdx.x;
    const ushort* A1 = flags[0] ? A1a : A1b;
#pragma unroll
    for (int i = 0; i < 16; ++i) {
        int f = i * 256 + t;
        int lane = f & 63, kk = (f >> 6) & 7, tile = f >> 9;
        int o = tile * 16 + (lane & 15);
        int k0 = kk * 32 + ((lane >> 4) * 8);
        const ushort* wsrc = (k0 < 128) ? (Wl + o * 128 + k0)
                                        : (Wr + o * 128 + (k0 - 128));
        *(short8*)&Ws[f * 8] = *(const short8*)wsrc;
    }
    __syncthreads();

    int wid = t >> 6, lane = t & 63;
    long nbase = (long)blockIdx.x * 64 + (long)wid * 16;
    int arow = (int)nbase + (lane & 15);
    if (arow >= N_NODES) arow = N_NODES - 1;   // clamp (stores guarded)
    int kq = (lane >> 4) * 8;

    short8 afrag[8];
#pragma unroll
    for (int kk = 0; kk < 8; ++kk) {
        int k0 = kk * 32 + kq;
        if (k0 < 128) {
            afrag[kk] = dec8(A0f8 + (long)arow * 128 + k0);
        } else if (layer1) {
            afrag[kk] = *(const short8*)(A1 + (long)arow * 128 + (k0 - 128));
        } else {
            afrag[kk] = dec8(A1f8 + (long)arow * 128 + (k0 - 128));
        }
    }

#pragma unroll
    for (int tile = 0; tile < 8; ++tile) {
        f32x4 acc = {0.f, 0.f, 0.f, 0.f};
#pragma unroll
        for (int kk = 0; kk < 8; ++kk) {
            short8 bfrag = *(short8*)&Ws[((tile * 8 + kk) * 64 + lane) * 8];
            acc = __builtin_amdgcn_mfma_f32_16x16x32_bf16(afrag[kk], bfrag, acc, 0, 0, 0);
        }
        int o = tile * 16 + (lane & 15);
        float bo = b2f(bias[o]);
#pragma unroll
        for (int r = 0; r < 4; ++r) {
            long node = nbase + (lane >> 4) * 4 + r;
            if (node < N_NODES) {
                float v = acc[r] + bo;
                v = v > 0.f ? v : 0.f;
                if (layer1) {
                    int pp = __builtin_amdgcn_cvt_pk_fp8_f32(v, v, 0, false);
                    out8[node * 128 + o] = (uchar)pp;
                } else {
                    outb[node * 128 + o] = f2b(v);
                }
            }
        }
    }
}

// ---- 7. fused global mean pool + classifier + log_softmax ----
__global__ __launch_bounds__(256) void k_pool_cls(const ushort* __restrict__ h2,
                                                  const void* __restrict__ batch,
                                                  const void* __restrict__ Wf,
                                                  const void* __restrict__ bfv,
                                                  void* __restrict__ outp,
                                                  const int* __restrict__ flags) {
    int g = blockIdx.x, t = threadIdx.x;
    int wid = t >> 6, lane = t & 63;
    bool f32 = (flags[0] == 0);
    int b64 = flags[2];
    __shared__ int rng[2];
    __shared__ float redA[4][64];
    __shared__ float redB[4][64];
    __shared__ float gv[128];
    __shared__ float lg[10];
    if (t < 2) {
        int v = g + t, lo = 0, hi = N_NODES;
        while (lo < hi) {
            int mid = (lo + hi) >> 1;
            if (idx_at(batch, mid, b64) < v) lo = mid + 1; else hi = mid;
        }
        rng[t] = lo;
    }
    __syncthreads();
    int lo = rng[0], hi = rng[1];
    const unsigned int* xr = (const unsigned int*)h2;
    float a0 = 0.f, a1 = 0.f;
    int n = lo + wid;
    for (; n + 28 < hi; n += 32) {
        unsigned int p[8];
#pragma unroll
        for (int i = 0; i < 8; ++i) p[i] = xr[(long)(n + i * 4) * 64 + lane];
#pragma unroll
        for (int i = 0; i < 8; ++i) { a0 += blo(p[i]); a1 += bhi(p[i]); }
    }
    for (; n < hi; n += 4) {
        unsigned int q = xr[(long)n * 64 + lane];
        a0 += blo(q); a1 += bhi(q);
    }
    redA[wid][lane] = a0;
    redB[wid][lane] = a1;
    __syncthreads();
    if (wid == 0) {
        float s0 = redA[0][lane] + redA[1][lane] + redA[2][lane] + redA[3][lane];
        float s1 = redB[0][lane] + redB[1][lane] + redB[2][lane] + redB[3][lane];
        float c = (hi > lo) ? (float)(hi - lo) : 1.f;
        gv[lane * 2]     = s0 / c;
        gv[lane * 2 + 1] = s1 / c;
    }
    __syncthreads();
    if (t < 10) {
        float s = f32 ? ((const float*)bfv)[t] : b2f(((const ushort*)bfv)[t]);
        for (int k = 0; k < 128; ++k) {
            float wv = f32 ? ((const float*)Wf)[t * 128 + k] : b2f(((const ushort*)Wf)[t * 128 + k]);
            s += gv[k] * wv;
        }
        lg[t] = s;
    }
    __syncthreads();
    if (t == 0) {
        float mx = lg[0];
        for (int i = 1; i < 10; ++i) mx = fmaxf(mx, lg[i]);
        float se = 0.f;
        for (int i = 0; i < 10; ++i) se += expf(lg[i] - mx);
        float lse = mx + logf(se);
        for (int i = 0; i < 10; ++i) {
            float v = lg[i] - lse;
            if (f32) ((float*)outp)[g * 10 + i] = v;
            else     ((ushort*)outp)[g * 10 + i] = f2b(v);
        }
    }
}

extern "C" void kernel_launch(void* const* d_in, const int* in_sizes, int n_in,
                              void* d_out, int out_size, void* d_ws, size_t ws_size,
                              hipStream_t stream) {
    const void* x     = d_in[0];
    const void* ei    = d_in[1];
    const void* batch = d_in[2];
    const void* W1l = d_in[3];
    const void* b1  = d_in[4];
    const void* W1r = d_in[5];
    const void* W2l = d_in[6];
    const void* b2  = d_in[7];
    const void* W2r = d_in[8];
    const void* Wf  = d_in[9];
    const void* bf_ = d_in[10];

    // workspace layout (aliased by lifetime; high-water 83,733,248 B)
    char* w = (char*)d_ws;
    int* flags      = (int*)(w + 0);              // 3 ints
    int* rowptr     = (int*)(w + 640);            // 100001 ints
    ushort* wbf     = (ushort*)(w + 400768);      // 65792 shorts
    int* csr        = (int*)(w + 532480);         // 1600064 ints (64 pad)
    ushort* xbf     = (ushort*)(w + 6933248);     // 25.6MB: x as bf16 (fp32 input); dead after gemm1
    ushort* h2      = (ushort*)(w + 6933248);     //   h2 bf16 reuses xbf region (written by gemm2)
    uchar* mbuf     = (uchar*)(w + 32533248);     // 12.8MB fp8 mean (CSR-era aliases below)
    int* bucketBase = (int*)(w + 32533248);       //   257 ints  (dead after k_csr)
    int* blkcnt     = (int*)(w + 32534528);       //   256*256   (dead after k_bscan)
    int* blkbase    = (int*)(w + 32796672);       //   256*256   (dead after k_bin)
    uchar* h1f8     = (uchar*)(w + 58133248);     // 12.8M fp8 h1
    int* binned     = (int*)(w + 58133248);       //   1.6M int packed (dead before gemm1)
    unsigned int* xf8 = (unsigned int*)(w + 70933248); // 12.8M fp8 x (as uints)

    dim3 blk256(256), blkNB(NB);

    k_detect<<<1, blk256, 0, stream>>>((const unsigned int*)x, (const unsigned int*)ei,
                                       (const int*)batch, flags);
    k_prep<<<NB + 2048 + 257, blk256, 0, stream>>>(ei, x, xbf, xf8,
                                                   W1l, W1r, W2l, W2r, b1, b2,
                                                   wbf, blkcnt, flags);
    k_bscan<<<1, blkNB, 0, stream>>>(blkcnt, bucketBase, blkbase);
    k_bin<<<NB, blk256, 0, stream>>>(ei, blkbase, binned, flags);
    k_csr<<<NB, blk256, 0, stream>>>(binned, bucketBase, rowptr, csr);

    int agrid = N_NODES / 4 / 4;                 // 6250 (4 nodes/wave, 4 waves/block)
    int ggrid = (N_NODES + 63) / 64;             // 1563

    // layer 1: agg over fp8 x -> mbuf(fp8); gemm (A0=mbuf fp8, A1=x bf16) -> h1f8 (fp8)
    k_agg<<<agrid, blk256, 0, stream>>>((const uint2*)xf8, rowptr, csr, (uint2*)mbuf);
    k_gemm<<<ggrid, blk256, 0, stream>>>(mbuf, (const ushort*)x, xbf, (const uchar*)nullptr,
                                         wbf + 0, wbf + 16384, wbf + 65536,
                                         (ushort*)nullptr, h1f8, flags, 1);
    // layer 2: agg over fp8 h1 -> mbuf; gemm (A0=mbuf fp8, A1=h1f8) -> h2 (bf16)
    k_agg<<<agrid, blk256, 0, stream>>>((const uint2*)h1f8, rowptr, csr, (uint2*)mbuf);
    k_gemm<<<ggrid, blk256, 0, stream>>>(mbuf, (const ushort*)x, xbf, h1f8,
                                         wbf + 32768, wbf + 49152, wbf + 65664,
                                         h2, (uchar*)nullptr, flags, 0);
    // pool + classify
    k_pool_cls<<<N_GRAPHS, blk256, 0, stream>>>(h2, batch, Wf, bf_, d_out, flags);
}